// Round 1
// baseline (6414.814 us; speedup 1.0000x reference)
//
#include <hip/hip_runtime.h>
#include <hip/hip_bf16.h>
#include <math.h>

#define B_ 8
#define L_ 1024
#define D_ 512
#define NB_ 4
#define DIN_ 1024
#define NST_ 16
#define DTR_ 32
#define FF_ 1024
#define EPS_LN 1e-5f

// ---------------------------------------------------------------------------
// Generic fp32 GEMM:  C[m,n] = epi( sum_k A[m,k] * W[n,k] + bias[n] )
// W is (N,K) row-major (all torch-style weights are (out,in)).
// MODE 0: A[m*lda + k]
// MODE 1: A is x (B,L,D); im2col with k = tap*512 + d, tap in {0,1,2}, pad 1
// EPI: 0 store, 1 +bias, 2 +bias+gelu(exact), 3 +bias+softplus,
//      4 C+=acc (residual), 5 C+=acc+bias (residual+bias)
// Tile 64x64, BK=16, 256 threads, 4x4 per thread.
// ---------------------------------------------------------------------------
template <int MODE, int EPI>
__global__ __launch_bounds__(256) void gemm_k(
    const float* __restrict__ A, const float* __restrict__ W,
    const float* __restrict__ bias, float* __restrict__ C,
    int M, int N, int K, int lda, int ldc)
{
  __shared__ __align__(16) float As[16][68];
  __shared__ __align__(16) float Bs[16][68];
  const int tid = threadIdx.x;
  const int bm = blockIdx.y * 64;
  const int bn = blockIdx.x * 64;
  const int tm = (tid & 15) * 4;
  const int tn = (tid >> 4) * 4;
  const int lr = tid >> 2;       // 0..63 : row within tile for loads
  const int lk = (tid & 3) * 4;  // 0,4,8,12 : k offset for loads

  float acc[4][4] = {};

  for (int k0 = 0; k0 < K; k0 += 16) {
    float4 av;
    if (MODE == 0) {
      av = *(const float4*)(A + (size_t)(bm + lr) * lda + k0 + lk);
    } else {
      const int kk = k0 + lk;
      const int tap = kk >> 9;      // 0..2 (float4 never crosses tap bound)
      const int d = kk & 511;
      const int m = bm + lr;
      const int l = (m & (L_ - 1)) + tap - 1;
      if (l >= 0 && l < L_)
        av = *(const float4*)(A + (size_t)(m - (m & (L_ - 1)) + l) * D_ + d);
      else
        av = make_float4(0.f, 0.f, 0.f, 0.f);
    }
    const float4 bv = *(const float4*)(W + (size_t)(bn + lr) * K + k0 + lk);
    As[lk + 0][lr] = av.x; As[lk + 1][lr] = av.y;
    As[lk + 2][lr] = av.z; As[lk + 3][lr] = av.w;
    Bs[lk + 0][lr] = bv.x; Bs[lk + 1][lr] = bv.y;
    Bs[lk + 2][lr] = bv.z; Bs[lk + 3][lr] = bv.w;
    __syncthreads();
#pragma unroll
    for (int k = 0; k < 16; ++k) {
      const float4 a = *(const float4*)&As[k][tm];
      const float4 b = *(const float4*)&Bs[k][tn];
      const float ar[4] = {a.x, a.y, a.z, a.w};
      const float br[4] = {b.x, b.y, b.z, b.w};
#pragma unroll
      for (int i = 0; i < 4; ++i)
#pragma unroll
        for (int j = 0; j < 4; ++j)
          acc[i][j] = fmaf(ar[i], br[j], acc[i][j]);
    }
    __syncthreads();
  }

#pragma unroll
  for (int i = 0; i < 4; ++i) {
    const int gm = bm + tm + i;
#pragma unroll
    for (int j = 0; j < 4; ++j) {
      const int gn = bn + tn + j;
      float v = acc[i][j];
      if (EPI == 1 || EPI == 2 || EPI == 3 || EPI == 5) v += bias[gn];
      if (EPI == 2) v = 0.5f * v * (1.f + erff(v * 0.70710678118654752f));
      if (EPI == 3) v = (v > 20.f) ? v : log1pf(expf(v));
      float* pc = C + (size_t)gm * ldc + gn;
      if (EPI == 4 || EPI == 5) v += *pc;
      *pc = v;
    }
  }
}

// ---------------------------------------------------------------------------
// LayerNorm over last dim D_=512; optional residual input (in+res).
// One 256-thread block per row; each thread owns 2 elements.
// ---------------------------------------------------------------------------
__global__ __launch_bounds__(256) void ln_k(
    const float* __restrict__ in, const float* __restrict__ res,
    const float* __restrict__ w, const float* __restrict__ b,
    float* __restrict__ out)
{
  const int row = blockIdx.x;
  const int t = threadIdx.x;
  const float* p = in + (size_t)row * D_;
  float v0 = p[t];
  float v1 = p[t + 256];
  if (res) {
    const float* r = res + (size_t)row * D_;
    v0 += r[t];
    v1 += r[t + 256];
  }
  float s = v0 + v1;
  float sq = v0 * v0 + v1 * v1;
#pragma unroll
  for (int m = 1; m < 64; m <<= 1) {
    s += __shfl_xor(s, m, 64);
    sq += __shfl_xor(sq, m, 64);
  }
  __shared__ float ss[4], qq[4];
  const int wid = t >> 6;
  if ((t & 63) == 0) { ss[wid] = s; qq[wid] = sq; }
  __syncthreads();
  s = ss[0] + ss[1] + ss[2] + ss[3];
  sq = qq[0] + qq[1] + qq[2] + qq[3];
  const float mu = s * (1.f / (float)D_);
  const float var = sq * (1.f / (float)D_) - mu * mu;
  const float rs = rsqrtf(var + EPS_LN);
  float* o = out + (size_t)row * D_;
  o[t] = (v0 - mu) * rs * w[t] + b[t];
  o[t + 256] = (v1 - mu) * rs * w[t + 256] + b[t + 256];
}

// ---------------------------------------------------------------------------
// Depthwise causal conv (k=4, left pad 3) over u-half of xz, + bias, + silu.
// One thread per (b,l,c); c fastest -> coalesced.
// ---------------------------------------------------------------------------
__global__ __launch_bounds__(256) void dwconv_k(
    const float* __restrict__ xz, const float* __restrict__ cw,
    const float* __restrict__ cb, float* __restrict__ u)
{
  const int idx = blockIdx.x * 256 + threadIdx.x;  // B*L*DIN = 2^23
  const int c = idx & (DIN_ - 1);
  const int bl = idx >> 10;           // b*L + l
  const int l = bl & (L_ - 1);
  const int b0 = bl - l;              // b*L
  float s = cb[c];
#pragma unroll
  for (int k = 0; k < 4; ++k) {
    const int ll = l + k - 3;
    if (ll >= 0)
      s = fmaf(xz[(size_t)(b0 + ll) * (2 * DIN_) + c], cw[c * 4 + k], s);
  }
  u[idx] = s / (1.f + __expf(-s));
}

// ---------------------------------------------------------------------------
// Selective scan. 16 lanes per (b,d) channel, one state n per lane.
// ys may alias u (read-before-write at the same slot).
// ---------------------------------------------------------------------------
__global__ __launch_bounds__(256) void scan_k(
    const float* __restrict__ dt, const float* u,
    const float* __restrict__ xdb, const float* __restrict__ xz,
    const float* __restrict__ A_log, const float* __restrict__ Dp,
    float* ys)
{
  const int tid = threadIdx.x;
  const int n = tid & 15;
  const int g = tid >> 4;                  // 16 groups per block
  const int gid = blockIdx.x * 16 + g;     // b*DIN + d
  const int b = gid >> 10;
  const int d = gid & (DIN_ - 1);
  const float Ad = -expf(A_log[d * NST_ + n]);
  const float Dpd = Dp[d];
  float h = 0.f;
  const size_t base = (size_t)b * L_;
  for (int l = 0; l < L_; ++l) {
    const size_t row = base + l;
    const float dtv = dt[row * DIN_ + d];
    const float uv = u[row * DIN_ + d];
    const float Bv = xdb[row * 64 + DTR_ + n];
    const float Cv = xdb[row * 64 + DTR_ + NST_ + n];
    h = __expf(dtv * Ad) * h + dtv * Bv * uv;
    float p = h * Cv;
    p += __shfl_xor(p, 1);
    p += __shfl_xor(p, 2);
    p += __shfl_xor(p, 4);
    p += __shfl_xor(p, 8);
    if (n == 0) {
      float y = p + uv * Dpd;
      const float z = xz[row * (2 * DIN_) + DIN_ + d];
      y *= z / (1.f + __expf(-z));
      ys[row * DIN_ + d] = y;
    }
  }
}

// ---------------------------------------------------------------------------
// Transpose tconv_w (O, I, 3) -> (O, tap*512 + d) so GEMM can float4-load K.
// ---------------------------------------------------------------------------
__global__ __launch_bounds__(256) void twt_k(const float* __restrict__ in,
                                             float* __restrict__ out)
{
  const int i = blockIdx.x * 256 + threadIdx.x;
  if (i >= D_ * D_ * 3) return;
  const int o = i / (D_ * 3);
  const int rem = i - o * (D_ * 3);
  const int d = rem / 3;
  const int tap = rem - d * 3;
  out[(size_t)o * (D_ * 3) + tap * D_ + d] = in[i];
}

// ---------------------------------------------------------------------------
extern "C" void kernel_launch(void* const* d_in, const int* in_sizes, int n_in,
                              void* d_out, int out_size, void* d_ws, size_t ws_size,
                              hipStream_t stream)
{
  const float* x         = (const float*)d_in[0];
  const float* tconv_w   = (const float*)d_in[1];
  const float* tconv_b   = (const float*)d_in[2];
  const float* tnorm_w   = (const float*)d_in[3];
  const float* tnorm_b   = (const float*)d_in[4];
  const float* ln1_w     = (const float*)d_in[5];
  const float* ln1_b     = (const float*)d_in[6];
  const float* in_proj_w = (const float*)d_in[7];
  const float* conv_w    = (const float*)d_in[8];
  const float* conv_b    = (const float*)d_in[9];
  const float* x_proj_w  = (const float*)d_in[10];
  const float* dt_proj_w = (const float*)d_in[11];
  const float* dt_proj_b = (const float*)d_in[12];
  const float* A_log     = (const float*)d_in[13];
  const float* D_param   = (const float*)d_in[14];
  const float* out_proj_w= (const float*)d_in[15];
  const float* ln2_w     = (const float*)d_in[16];
  const float* ln2_b     = (const float*)d_in[17];
  const float* ffn_w1    = (const float*)d_in[18];
  const float* ffn_b1    = (const float*)d_in[19];
  const float* ffn_w2    = (const float*)d_in[20];
  const float* ffn_b2    = (const float*)d_in[21];

  float* h = (float*)d_out;              // h lives in d_out throughout
  const int M = B_ * L_;                 // 8192

  // workspace layout (floats)
  float* ws    = (float*)d_ws;
  float* wTT   = ws;                     // 512*1536      =   786432
  float* wsA   = wTT + 786432;           // M*512         =  4194304 (xin / hn / hc)
  float* wsXZ  = wsA + (size_t)M * D_;   // M*2048        = 16777216
  float* wsU   = wsXZ + (size_t)M * 2 * DIN_; // M*1024   =  8388608 (u, then ys in place)
  float* wsXDB = wsU + (size_t)M * DIN_; // M*64          =   524288
  float* wsDT  = wsXDB + (size_t)M * 64; // M*1024        =  8388608 (dt, then ff)

  const dim3 blk(256);

  // --- temporal conv (as GEMM with fused im2col) + LN(hc + x) -> h ---
  twt_k<<<dim3((D_ * D_ * 3 + 255) / 256), blk, 0, stream>>>(tconv_w, wTT);
  gemm_k<1, 1><<<dim3(D_ / 64, M / 64), blk, 0, stream>>>(
      x, wTT, tconv_b, wsA, M, D_, D_ * 3, 0, D_);
  ln_k<<<dim3(M), blk, 0, stream>>>(wsA, x, tnorm_w, tnorm_b, h);

  for (int i = 0; i < NB_; ++i) {
    const float* ipw = in_proj_w + (size_t)i * 2 * DIN_ * D_;
    const float* cw  = conv_w + (size_t)i * DIN_ * 4;
    const float* cb  = conv_b + (size_t)i * DIN_;
    const float* xpw = x_proj_w + (size_t)i * 64 * DIN_;
    const float* dtw = dt_proj_w + (size_t)i * DIN_ * DTR_;
    const float* dtb = dt_proj_b + (size_t)i * DIN_;
    const float* Al  = A_log + (size_t)i * DIN_ * NST_;
    const float* Dpp = D_param + (size_t)i * DIN_;
    const float* opw = out_proj_w + (size_t)i * D_ * DIN_;

    // xin = LN(h)
    ln_k<<<dim3(M), blk, 0, stream>>>(h, nullptr, ln1_w + i * D_, ln1_b + i * D_, wsA);
    // xz = xin @ in_proj^T
    gemm_k<0, 0><<<dim3(2 * DIN_ / 64, M / 64), blk, 0, stream>>>(
        wsA, ipw, nullptr, wsXZ, M, 2 * DIN_, D_, D_, 2 * DIN_);
    // u = silu(causal depthwise conv(u) + cb)
    dwconv_k<<<dim3(M * DIN_ / 256), blk, 0, stream>>>(wsXZ, cw, cb, wsU);
    // xdb = u @ x_proj^T
    gemm_k<0, 0><<<dim3(64 / 64, M / 64), blk, 0, stream>>>(
        wsU, xpw, nullptr, wsXDB, M, 64, DIN_, DIN_, 64);
    // dt = softplus(xdb[:, :32] @ dt_proj^T + dtb)
    gemm_k<0, 3><<<dim3(DIN_ / 64, M / 64), blk, 0, stream>>>(
        wsXDB, dtw, dtb, wsDT, M, DIN_, DTR_, 64, DIN_);
    // selective scan (+ D*u, * silu(z)); ys overwrites u in place
    scan_k<<<dim3(B_ * DIN_ / 16), blk, 0, stream>>>(
        wsDT, wsU, wsXDB, wsXZ, Al, Dpp, wsU);
    // h += ys @ out_proj^T
    gemm_k<0, 4><<<dim3(D_ / 64, M / 64), blk, 0, stream>>>(
        wsU, opw, nullptr, h, M, D_, DIN_, DIN_, D_);
    // hn = LN(h);  ff = gelu(hn @ w1^T + b1);  h += ff @ w2^T + b2
    ln_k<<<dim3(M), blk, 0, stream>>>(h, nullptr, ln2_w + i * D_, ln2_b + i * D_, wsA);
    gemm_k<0, 2><<<dim3(FF_ / 64, M / 64), blk, 0, stream>>>(
        wsA, ffn_w1 + (size_t)i * FF_ * D_, ffn_b1 + (size_t)i * FF_, wsDT,
        M, FF_, D_, D_, FF_);
    gemm_k<0, 5><<<dim3(D_ / 64, M / 64), blk, 0, stream>>>(
        wsDT, ffn_w2 + (size_t)i * D_ * FF_, ffn_b2 + (size_t)i * D_, h,
        M, D_, FF_, FF_, D_);
  }
}

// Round 2
// 3370.511 us; speedup vs baseline: 1.9032x; 1.9032x over previous
//
#include <hip/hip_runtime.h>
#include <hip/hip_bf16.h>
#include <math.h>

#define B_ 8
#define L_ 1024
#define D_ 512
#define NB_ 4
#define DIN_ 1024
#define NST_ 16
#define DTR_ 32
#define FF_ 1024
#define EPS_LN 1e-5f

typedef __attribute__((ext_vector_type(8))) short short8;
typedef __attribute__((ext_vector_type(4))) float f32x4;

static __device__ __forceinline__ ushort f2bf(float f) {
  union { float f; unsigned u; } v; v.f = f;
  unsigned r = v.u + 0x7FFFu + ((v.u >> 16) & 1u);
  return (ushort)(r >> 16);
}

// ---------------------------------------------------------------------------
// bf16 MFMA GEMM:  C[m,n] = epi( sum_k A[m,k] * W[n,k] (+ bias[n]) )
// A,W fp32 in global; converted to bf16 during LDS staging.
// Tile 128 x BN, BK=32, 256 threads = 4 waves (2x2), wave tile 64 x BN/2.
// MODE 0: A[m*lda+k].  MODE 1: im2col of x (B,L,D), k = tap*512+d, pad 1.
// EPI: 0 store, 1 +bias, 2 +bias+gelu, 3 +bias+softplus, 4 C+=, 5 C+=+bias
// LDS XOR-swizzle on 16B k-groups: kq' = kq ^ ((row>>1)&3)  (2-way = free).
// ---------------------------------------------------------------------------
template <int MODE, int EPI, int BN>
__global__ __launch_bounds__(256) void mgemm_k(
    const float* __restrict__ A, const float* __restrict__ W,
    const float* __restrict__ bias, float* __restrict__ C,
    int M, int N, int K, int lda, int ldc)
{
  constexpr int FN = BN / 32;
  __shared__ ushort As[128 * 32];
  __shared__ ushort Bs[BN * 32];
  const int tid = threadIdx.x;
  const int lane = tid & 63;
  const int wid = tid >> 6;
  const int wm = (wid >> 1) * 64;
  const int wn = (wid & 1) * (BN / 2);
  const int bm = blockIdx.y * 128;
  const int bn = blockIdx.x * BN;
  const int fr = lane & 15;
  const int kq = lane >> 4;

  f32x4 acc[4][FN];
#pragma unroll
  for (int i = 0; i < 4; ++i)
#pragma unroll
    for (int j = 0; j < FN; ++j) acc[i][j] = (f32x4)0.f;

  for (int k0 = 0; k0 < K; k0 += 32) {
    // ---- stage A tile (128 x 32) ----
#pragma unroll
    for (int it = 0; it < 4; ++it) {
      const int idx = tid + it * 256;
      const int row = idx >> 3;
      const int j = idx & 7;
      float4 v;
      if (MODE == 0) {
        v = *(const float4*)(A + (size_t)(bm + row) * lda + k0 + j * 4);
      } else {
        const int kk = k0 + j * 4;
        const int tap = kk >> 9;
        const int dcol = kk & 511;
        const int m = bm + row;
        const int l = (m & (L_ - 1)) + tap - 1;
        if (l >= 0 && l < L_)
          v = *(const float4*)(A + (size_t)(m - (m & (L_ - 1)) + l) * D_ + dcol);
        else
          v = make_float4(0.f, 0.f, 0.f, 0.f);
      }
      ushort4 s;
      s.x = f2bf(v.x); s.y = f2bf(v.y); s.z = f2bf(v.z); s.w = f2bf(v.w);
      const int off = row * 32 + (((j >> 1) ^ ((row >> 1) & 3)) << 3) + (j & 1) * 4;
      *(ushort4*)&As[off] = s;
    }
    // ---- stage B tile (BN x 32) ----
#pragma unroll
    for (int it = 0; it < BN / 32; ++it) {
      const int idx = tid + it * 256;
      const int row = idx >> 3;
      const int j = idx & 7;
      const float4 v = *(const float4*)(W + (size_t)(bn + row) * K + k0 + j * 4);
      ushort4 s;
      s.x = f2bf(v.x); s.y = f2bf(v.y); s.z = f2bf(v.z); s.w = f2bf(v.w);
      const int off = row * 32 + (((j >> 1) ^ ((row >> 1) & 3)) << 3) + (j & 1) * 4;
      *(ushort4*)&Bs[off] = s;
    }
    __syncthreads();
    short8 af[4], bfr[FN];
#pragma unroll
    for (int mi = 0; mi < 4; ++mi) {
      const int r = wm + mi * 16 + fr;
      af[mi] = *(const short8*)&As[r * 32 + ((kq ^ ((r >> 1) & 3)) << 3)];
    }
#pragma unroll
    for (int ni = 0; ni < FN; ++ni) {
      const int r = wn + ni * 16 + fr;
      bfr[ni] = *(const short8*)&Bs[r * 32 + ((kq ^ ((r >> 1) & 3)) << 3)];
    }
#pragma unroll
    for (int mi = 0; mi < 4; ++mi)
#pragma unroll
      for (int ni = 0; ni < FN; ++ni)
        acc[mi][ni] = __builtin_amdgcn_mfma_f32_16x16x32_bf16(
            af[mi], bfr[ni], acc[mi][ni], 0, 0, 0);
    __syncthreads();
  }

  // ---- epilogue: D layout col=lane&15, row=(lane>>4)*4+reg ----
#pragma unroll
  for (int mi = 0; mi < 4; ++mi) {
#pragma unroll
    for (int ni = 0; ni < FN; ++ni) {
#pragma unroll
      for (int r = 0; r < 4; ++r) {
        const int gm = bm + wm + mi * 16 + (lane >> 4) * 4 + r;
        const int gn = bn + wn + ni * 16 + fr;
        float v = acc[mi][ni][r];
        if (EPI == 1 || EPI == 2 || EPI == 3 || EPI == 5) v += bias[gn];
        if (EPI == 2) v = 0.5f * v * (1.f + erff(v * 0.70710678118654752f));
        if (EPI == 3) v = (v > 20.f) ? v : log1pf(__expf(v));
        float* pc = C + (size_t)gm * ldc + gn;
        if (EPI == 4 || EPI == 5) v += *pc;
        *pc = v;
      }
    }
  }
}

// ---------------------------------------------------------------------------
// LayerNorm over last dim 512; optional residual (in+res).
// ---------------------------------------------------------------------------
__global__ __launch_bounds__(256) void ln_k(
    const float* __restrict__ in, const float* __restrict__ res,
    const float* __restrict__ w, const float* __restrict__ b,
    float* __restrict__ out)
{
  const int row = blockIdx.x;
  const int t = threadIdx.x;
  const float* p = in + (size_t)row * D_;
  float v0 = p[t];
  float v1 = p[t + 256];
  if (res) {
    const float* r = res + (size_t)row * D_;
    v0 += r[t];
    v1 += r[t + 256];
  }
  float s = v0 + v1;
  float sq = v0 * v0 + v1 * v1;
#pragma unroll
  for (int m = 1; m < 64; m <<= 1) {
    s += __shfl_xor(s, m, 64);
    sq += __shfl_xor(sq, m, 64);
  }
  __shared__ float ss[4], qq[4];
  const int wid = t >> 6;
  if ((t & 63) == 0) { ss[wid] = s; qq[wid] = sq; }
  __syncthreads();
  s = ss[0] + ss[1] + ss[2] + ss[3];
  sq = qq[0] + qq[1] + qq[2] + qq[3];
  const float mu = s * (1.f / (float)D_);
  const float var = sq * (1.f / (float)D_) - mu * mu;
  const float rs = rsqrtf(var + EPS_LN);
  float* o = out + (size_t)row * D_;
  o[t] = (v0 - mu) * rs * w[t] + b[t];
  o[t + 256] = (v1 - mu) * rs * w[t + 256] + b[t + 256];
}

// ---------------------------------------------------------------------------
// Depthwise causal conv (k=4, pad 3) over u-half of xz, + bias, + silu.
// ---------------------------------------------------------------------------
__global__ __launch_bounds__(256) void dwconv_k(
    const float* __restrict__ xz, const float* __restrict__ cw,
    const float* __restrict__ cb, float* __restrict__ u)
{
  const int idx = blockIdx.x * 256 + threadIdx.x;
  const int c = idx & (DIN_ - 1);
  const int bl = idx >> 10;
  const int l = bl & (L_ - 1);
  const int b0 = bl - l;
  float s = cb[c];
#pragma unroll
  for (int k = 0; k < 4; ++k) {
    const int ll = l + k - 3;
    if (ll >= 0)
      s = fmaf(xz[(size_t)(b0 + ll) * (2 * DIN_) + c], cw[c * 4 + k], s);
  }
  u[idx] = s / (1.f + __expf(-s));
}

// ---------------------------------------------------------------------------
// Chunked selective scan. One block per (b,d): 512 thr = 32 chunks x 16 states.
// Pass 1: per-chunk decay P=exp(sum dt*A) and local end-state H.
// Serial combine (16 threads, 32 steps) -> incoming state per chunk.
// Pass 2: recompute chunk with corrected h, emit y (*silu(z), +D*u).
// ys may alias u (read-before-write at same slot, chunks disjoint).
// ---------------------------------------------------------------------------
__global__ __launch_bounds__(512) void scan2_k(
    const float* __restrict__ dt, const float* u,
    const float* __restrict__ xdb, const float* __restrict__ xz,
    const float* __restrict__ A_log, const float* __restrict__ Dp,
    float* ys)
{
  const int tid = threadIdx.x;
  const int n = tid & 15;
  const int c = tid >> 4;                 // 32 chunks of 32 steps
  const int gid = blockIdx.x;             // b*DIN + d
  const int b = gid >> 10;
  const int d = gid & (DIN_ - 1);
  const float Ad = -expf(A_log[d * NST_ + n]);
  const float Dpd = Dp[d];
  const size_t base = (size_t)b * L_;
  const int l0 = c * 32;

  __shared__ float Ps[32][16], Hs[32][16], Hin[32][16];

  float h = 0.f, S = 0.f;
  for (int l = l0; l < l0 + 32; ++l) {
    const size_t row = base + l;
    const float dtv = dt[row * DIN_ + d];
    const float uv = u[row * DIN_ + d];
    const float Bv = xdb[row * 64 + DTR_ + n];
    const float xa = dtv * Ad;
    S += xa;
    h = __expf(xa) * h + dtv * Bv * uv;
  }
  Ps[c][n] = __expf(S);
  Hs[c][n] = h;
  __syncthreads();
  if (tid < 16) {
    float hin = 0.f;
    for (int cc = 0; cc < 32; ++cc) {
      Hin[cc][tid] = hin;
      hin = Hs[cc][tid] + Ps[cc][tid] * hin;
    }
  }
  __syncthreads();
  h = Hin[c][n];

  for (int l = l0; l < l0 + 32; ++l) {
    const size_t row = base + l;
    const float dtv = dt[row * DIN_ + d];
    const float uv = u[row * DIN_ + d];
    const float Bv = xdb[row * 64 + DTR_ + n];
    const float Cv = xdb[row * 64 + DTR_ + NST_ + n];
    h = __expf(dtv * Ad) * h + dtv * Bv * uv;
    float p = h * Cv;
    p += __shfl_xor(p, 1);
    p += __shfl_xor(p, 2);
    p += __shfl_xor(p, 4);
    p += __shfl_xor(p, 8);
    if (n == 0) {
      float y = p + uv * Dpd;
      const float z = xz[row * (2 * DIN_) + DIN_ + d];
      y *= z / (1.f + __expf(-z));
      ys[row * DIN_ + d] = y;
    }
  }
}

// ---------------------------------------------------------------------------
// Transpose tconv_w (O,I,3) -> (O, tap*512 + d).
// ---------------------------------------------------------------------------
__global__ __launch_bounds__(256) void twt_k(const float* __restrict__ in,
                                             float* __restrict__ out)
{
  const int i = blockIdx.x * 256 + threadIdx.x;
  if (i >= D_ * D_ * 3) return;
  const int o = i / (D_ * 3);
  const int rem = i - o * (D_ * 3);
  const int d = rem / 3;
  const int tap = rem - d * 3;
  out[(size_t)o * (D_ * 3) + tap * D_ + d] = in[i];
}

// ---------------------------------------------------------------------------
extern "C" void kernel_launch(void* const* d_in, const int* in_sizes, int n_in,
                              void* d_out, int out_size, void* d_ws, size_t ws_size,
                              hipStream_t stream)
{
  const float* x         = (const float*)d_in[0];
  const float* tconv_w   = (const float*)d_in[1];
  const float* tconv_b   = (const float*)d_in[2];
  const float* tnorm_w   = (const float*)d_in[3];
  const float* tnorm_b   = (const float*)d_in[4];
  const float* ln1_w     = (const float*)d_in[5];
  const float* ln1_b     = (const float*)d_in[6];
  const float* in_proj_w = (const float*)d_in[7];
  const float* conv_w    = (const float*)d_in[8];
  const float* conv_b    = (const float*)d_in[9];
  const float* x_proj_w  = (const float*)d_in[10];
  const float* dt_proj_w = (const float*)d_in[11];
  const float* dt_proj_b = (const float*)d_in[12];
  const float* A_log     = (const float*)d_in[13];
  const float* D_param   = (const float*)d_in[14];
  const float* out_proj_w= (const float*)d_in[15];
  const float* ln2_w     = (const float*)d_in[16];
  const float* ln2_b     = (const float*)d_in[17];
  const float* ffn_w1    = (const float*)d_in[18];
  const float* ffn_b1    = (const float*)d_in[19];
  const float* ffn_w2    = (const float*)d_in[20];
  const float* ffn_b2    = (const float*)d_in[21];

  float* h = (float*)d_out;
  const int M = B_ * L_;  // 8192

  float* ws    = (float*)d_ws;
  float* wTT   = ws;                          // 786432
  float* wsA   = wTT + 786432;                // M*512
  float* wsXZ  = wsA + (size_t)M * D_;        // M*2048
  float* wsU   = wsXZ + (size_t)M * 2 * DIN_; // M*1024 (u, ys in place)
  float* wsXDB = wsU + (size_t)M * DIN_;      // M*64
  float* wsDT  = wsXDB + (size_t)M * 64;      // M*1024 (dt, then ff)

  const dim3 blk(256);

  // temporal conv (GEMM + fused im2col) + LN(hc + x) -> h
  twt_k<<<dim3((D_ * D_ * 3 + 255) / 256), blk, 0, stream>>>(tconv_w, wTT);
  mgemm_k<1, 1, 128><<<dim3(D_ / 128, M / 128), blk, 0, stream>>>(
      x, wTT, tconv_b, wsA, M, D_, D_ * 3, 0, D_);
  ln_k<<<dim3(M), blk, 0, stream>>>(wsA, x, tnorm_w, tnorm_b, h);

  for (int i = 0; i < NB_; ++i) {
    const float* ipw = in_proj_w + (size_t)i * 2 * DIN_ * D_;
    const float* cw  = conv_w + (size_t)i * DIN_ * 4;
    const float* cb  = conv_b + (size_t)i * DIN_;
    const float* xpw = x_proj_w + (size_t)i * 64 * DIN_;
    const float* dtw = dt_proj_w + (size_t)i * DIN_ * DTR_;
    const float* dtb = dt_proj_b + (size_t)i * DIN_;
    const float* Al  = A_log + (size_t)i * DIN_ * NST_;
    const float* Dpp = D_param + (size_t)i * DIN_;
    const float* opw = out_proj_w + (size_t)i * D_ * DIN_;

    // xin = LN(h)
    ln_k<<<dim3(M), blk, 0, stream>>>(h, nullptr, ln1_w + i * D_, ln1_b + i * D_, wsA);
    // xz = xin @ in_proj^T
    mgemm_k<0, 0, 128><<<dim3(2 * DIN_ / 128, M / 128), blk, 0, stream>>>(
        wsA, ipw, nullptr, wsXZ, M, 2 * DIN_, D_, D_, 2 * DIN_);
    // u = silu(dwconv(u) + cb)
    dwconv_k<<<dim3(M * DIN_ / 256), blk, 0, stream>>>(wsXZ, cw, cb, wsU);
    // xdb = u @ x_proj^T   (N=64)
    mgemm_k<0, 0, 64><<<dim3(1, M / 128), blk, 0, stream>>>(
        wsU, xpw, nullptr, wsXDB, M, 64, DIN_, DIN_, 64);
    // dt = softplus(xdb[:, :32] @ dt_proj^T + dtb)   (K=32)
    mgemm_k<0, 3, 128><<<dim3(DIN_ / 128, M / 128), blk, 0, stream>>>(
        wsXDB, dtw, dtb, wsDT, M, DIN_, DTR_, 64, DIN_);
    // selective scan; ys overwrites u in place
    scan2_k<<<dim3(B_ * DIN_), dim3(512), 0, stream>>>(
        wsDT, wsU, wsXDB, wsXZ, Al, Dpp, wsU);
    // h += ys @ out_proj^T
    mgemm_k<0, 4, 128><<<dim3(D_ / 128, M / 128), blk, 0, stream>>>(
        wsU, opw, nullptr, h, M, D_, DIN_, DIN_, D_);
    // hn = LN(h); ff = gelu(hn @ w1^T + b1); h += ff @ w2^T + b2
    ln_k<<<dim3(M), blk, 0, stream>>>(h, nullptr, ln2_w + i * D_, ln2_b + i * D_, wsA);
    mgemm_k<0, 2, 128><<<dim3(FF_ / 128, M / 128), blk, 0, stream>>>(
        wsA, ffn_w1 + (size_t)i * FF_ * D_, ffn_b1 + (size_t)i * FF_, wsDT,
        M, FF_, D_, D_, FF_);
    mgemm_k<0, 5, 128><<<dim3(D_ / 128, M / 128), blk, 0, stream>>>(
        wsDT, ffn_w2 + (size_t)i * D_ * FF_, ffn_b2 + (size_t)i * D_, h,
        M, D_, FF_, FF_, D_);
  }
}

// Round 4
// 2145.660 us; speedup vs baseline: 2.9897x; 1.5709x over previous
//
#include <hip/hip_runtime.h>
#include <hip/hip_bf16.h>
#include <math.h>

#define B_ 8
#define L_ 1024
#define D_ 512
#define NB_ 4
#define DIN_ 1024
#define NST_ 16
#define DTR_ 32
#define FF_ 1024
#define EPS_LN 1e-5f

#define SC_G 32                 // channels per scan block
#define SC_C 16                 // L-chunks per scan block
#define SC_LEN (L_ / SC_C)      // 64 steps per chunk

typedef __attribute__((ext_vector_type(8))) short short8;
typedef __attribute__((ext_vector_type(4))) float f32x4;

static __device__ __forceinline__ ushort f2bf(float f) {
  union { float f; unsigned u; } v; v.f = f;
  unsigned r = v.u + 0x7FFFu + ((v.u >> 16) & 1u);
  return (ushort)(r >> 16);
}

// ---------------------------------------------------------------------------
// bf16 MFMA GEMM:  C[m,n] = epi( sum_k A[m,k] * W[n,k] (+ bias[n]) )
// A,W fp32 in global; converted to bf16 during LDS staging.
// Tile 128 x BN, BK=32, 256 threads = 4 waves (2x2), wave tile 64 x BN/2.
// MODE 0: A[m*lda+k].  MODE 1: im2col of x (B,L,D), k = tap*512+d, pad 1.
// EPI: 0 store, 1 +bias, 2 +bias+gelu, 3 +bias+softplus, 4 C+=, 5 C+=+bias
// ---------------------------------------------------------------------------
template <int MODE, int EPI, int BN>
__global__ __launch_bounds__(256) void mgemm_k(
    const float* __restrict__ A, const float* __restrict__ W,
    const float* __restrict__ bias, float* __restrict__ C,
    int M, int N, int K, int lda, int ldc)
{
  constexpr int FN = BN / 32;
  __shared__ ushort As[128 * 32];
  __shared__ ushort Bs[BN * 32];
  const int tid = threadIdx.x;
  const int lane = tid & 63;
  const int wid = tid >> 6;
  const int wm = (wid >> 1) * 64;
  const int wn = (wid & 1) * (BN / 2);
  const int bm = blockIdx.y * 128;
  const int bn = blockIdx.x * BN;
  const int fr = lane & 15;
  const int kq = lane >> 4;

  f32x4 acc[4][FN];
#pragma unroll
  for (int i = 0; i < 4; ++i)
#pragma unroll
    for (int j = 0; j < FN; ++j) acc[i][j] = (f32x4)0.f;

  for (int k0 = 0; k0 < K; k0 += 32) {
#pragma unroll
    for (int it = 0; it < 4; ++it) {
      const int idx = tid + it * 256;
      const int row = idx >> 3;
      const int j = idx & 7;
      float4 v;
      if (MODE == 0) {
        v = *(const float4*)(A + (size_t)(bm + row) * lda + k0 + j * 4);
      } else {
        const int kk = k0 + j * 4;
        const int tap = kk >> 9;
        const int dcol = kk & 511;
        const int m = bm + row;
        const int l = (m & (L_ - 1)) + tap - 1;
        if (l >= 0 && l < L_)
          v = *(const float4*)(A + (size_t)(m - (m & (L_ - 1)) + l) * D_ + dcol);
        else
          v = make_float4(0.f, 0.f, 0.f, 0.f);
      }
      ushort4 s;
      s.x = f2bf(v.x); s.y = f2bf(v.y); s.z = f2bf(v.z); s.w = f2bf(v.w);
      const int off = row * 32 + (((j >> 1) ^ ((row >> 1) & 3)) << 3) + (j & 1) * 4;
      *(ushort4*)&As[off] = s;
    }
#pragma unroll
    for (int it = 0; it < BN / 32; ++it) {
      const int idx = tid + it * 256;
      const int row = idx >> 3;
      const int j = idx & 7;
      const float4 v = *(const float4*)(W + (size_t)(bn + row) * K + k0 + j * 4);
      ushort4 s;
      s.x = f2bf(v.x); s.y = f2bf(v.y); s.z = f2bf(v.z); s.w = f2bf(v.w);
      const int off = row * 32 + (((j >> 1) ^ ((row >> 1) & 3)) << 3) + (j & 1) * 4;
      *(ushort4*)&Bs[off] = s;
    }
    __syncthreads();
    short8 af[4], bfr[FN];
#pragma unroll
    for (int mi = 0; mi < 4; ++mi) {
      const int r = wm + mi * 16 + fr;
      af[mi] = *(const short8*)&As[r * 32 + ((kq ^ ((r >> 1) & 3)) << 3)];
    }
#pragma unroll
    for (int ni = 0; ni < FN; ++ni) {
      const int r = wn + ni * 16 + fr;
      bfr[ni] = *(const short8*)&Bs[r * 32 + ((kq ^ ((r >> 1) & 3)) << 3)];
    }
#pragma unroll
    for (int mi = 0; mi < 4; ++mi)
#pragma unroll
      for (int ni = 0; ni < FN; ++ni)
        acc[mi][ni] = __builtin_amdgcn_mfma_f32_16x16x32_bf16(
            af[mi], bfr[ni], acc[mi][ni], 0, 0, 0);
    __syncthreads();
  }

#pragma unroll
  for (int mi = 0; mi < 4; ++mi) {
#pragma unroll
    for (int ni = 0; ni < FN; ++ni) {
#pragma unroll
      for (int r = 0; r < 4; ++r) {
        const int gm = bm + wm + mi * 16 + (lane >> 4) * 4 + r;
        const int gn = bn + wn + ni * 16 + fr;
        float v = acc[mi][ni][r];
        if (EPI == 1 || EPI == 2 || EPI == 3 || EPI == 5) v += bias[gn];
        if (EPI == 2) v = 0.5f * v * (1.f + erff(v * 0.70710678118654752f));
        if (EPI == 3) v = (v > 20.f) ? v : log1pf(__expf(v));
        float* pc = C + (size_t)gm * ldc + gn;
        if (EPI == 4 || EPI == 5) v += *pc;
        *pc = v;
      }
    }
  }
}

// ---------------------------------------------------------------------------
// LayerNorm over last dim 512; optional residual (in+res).
// ---------------------------------------------------------------------------
__global__ __launch_bounds__(256) void ln_k(
    const float* __restrict__ in, const float* __restrict__ res,
    const float* __restrict__ w, const float* __restrict__ b,
    float* __restrict__ out)
{
  const int row = blockIdx.x;
  const int t = threadIdx.x;
  const float* p = in + (size_t)row * D_;
  float v0 = p[t];
  float v1 = p[t + 256];
  if (res) {
    const float* r = res + (size_t)row * D_;
    v0 += r[t];
    v1 += r[t + 256];
  }
  float s = v0 + v1;
  float sq = v0 * v0 + v1 * v1;
#pragma unroll
  for (int m = 1; m < 64; m <<= 1) {
    s += __shfl_xor(s, m, 64);
    sq += __shfl_xor(sq, m, 64);
  }
  __shared__ float ss[4], qq[4];
  const int wid = t >> 6;
  if ((t & 63) == 0) { ss[wid] = s; qq[wid] = sq; }
  __syncthreads();
  s = ss[0] + ss[1] + ss[2] + ss[3];
  sq = qq[0] + qq[1] + qq[2] + qq[3];
  const float mu = s * (1.f / (float)D_);
  const float var = sq * (1.f / (float)D_) - mu * mu;
  const float rs = rsqrtf(var + EPS_LN);
  float* o = out + (size_t)row * D_;
  o[t] = (v0 - mu) * rs * w[t] + b[t];
  o[t + 256] = (v1 - mu) * rs * w[t + 256] + b[t + 256];
}

// ---------------------------------------------------------------------------
// Depthwise causal conv (k=4, pad 3) over u-half of xz, + bias, + silu.
// ---------------------------------------------------------------------------
__global__ __launch_bounds__(256) void dwconv_k(
    const float* __restrict__ xz, const float* __restrict__ cw,
    const float* __restrict__ cb, float* __restrict__ u)
{
  const int idx = blockIdx.x * 256 + threadIdx.x;
  const int c = idx & (DIN_ - 1);
  const int bl = idx >> 10;
  const int l = bl & (L_ - 1);
  const int b0 = bl - l;
  float s = cb[c];
#pragma unroll
  for (int k = 0; k < 4; ++k) {
    const int ll = l + k - 3;
    if (ll >= 0)
      s = fmaf(xz[(size_t)(b0 + ll) * (2 * DIN_) + c], cw[c * 4 + k], s);
  }
  u[idx] = s / (1.f + __expf(-s));
}

// ---------------------------------------------------------------------------
// Coalesced chunked selective scan.
// Block = (b, 32-channel group). 512 thr = 32 channels x 16 chunks (64 steps).
// Each thread owns all 16 states of one channel (registers, static index).
// dt/u/z reads + ys writes coalesced across channels; B/C are wave-uniform
// float4 broadcasts. Chunk decay P_n = exp(A_n * sum(dt)) is exact.
// ys may alias u (each (row,d) owned by one thread, read-before-write).
// ---------------------------------------------------------------------------
__global__ __launch_bounds__(512) void scan3_k(
    const float* __restrict__ dt, const float* u,
    const float* __restrict__ xdb, const float* __restrict__ xz,
    const float* __restrict__ A_log, const float* __restrict__ Dp,
    float* ys)
{
  const int tid = threadIdx.x;
  const int g = tid & (SC_G - 1);
  const int c = tid >> 5;                    // chunk index 0..15
  const int b = blockIdx.x >> 5;
  const int d0 = (blockIdx.x & 31) * SC_G;
  const int d = d0 + g;

  __shared__ float Hs[SC_C][SC_G][NST_ + 1]; // padded: no bank conflicts
  __shared__ float Ss[SC_C][SC_G];

  float A[16];
#pragma unroll
  for (int n = 0; n < 16; ++n) A[n] = -expf(A_log[d * NST_ + n]);
  const float Dpd = Dp[d];

  const size_t base = (size_t)b * L_;
  const int l0 = c * SC_LEN;

  // ---------------- pass 1: local scan + decay sum ----------------
  float h[16];
#pragma unroll
  for (int n = 0; n < 16; ++n) h[n] = 0.f;
  float S = 0.f;
  {
    size_t row = base + l0;
    float dtv = dt[row * DIN_ + d];
    float uv = u[row * DIN_ + d];
    float Bv[16];
    *(float4*)&Bv[0]  = *(const float4*)(xdb + row * 64 + DTR_);
    *(float4*)&Bv[4]  = *(const float4*)(xdb + row * 64 + DTR_ + 4);
    *(float4*)&Bv[8]  = *(const float4*)(xdb + row * 64 + DTR_ + 8);
    *(float4*)&Bv[12] = *(const float4*)(xdb + row * 64 + DTR_ + 12);
    for (int i = 0; i < SC_LEN; ++i) {
      // prefetch next step
      float ndt = 0.f, nu = 0.f;
      float NB[16];
      if (i + 1 < SC_LEN) {
        const size_t nrow = row + 1;
        ndt = dt[nrow * DIN_ + d];
        nu = u[nrow * DIN_ + d];
        *(float4*)&NB[0]  = *(const float4*)(xdb + nrow * 64 + DTR_);
        *(float4*)&NB[4]  = *(const float4*)(xdb + nrow * 64 + DTR_ + 4);
        *(float4*)&NB[8]  = *(const float4*)(xdb + nrow * 64 + DTR_ + 8);
        *(float4*)&NB[12] = *(const float4*)(xdb + nrow * 64 + DTR_ + 12);
      }
      S += dtv;
      const float du = dtv * uv;
#pragma unroll
      for (int n = 0; n < 16; ++n)
        h[n] = __expf(dtv * A[n]) * h[n] + du * Bv[n];
      dtv = ndt; uv = nu;
#pragma unroll
      for (int n = 0; n < 16; ++n) Bv[n] = NB[n];
      row += 1;
    }
  }
#pragma unroll
  for (int n = 0; n < 16; ++n) Hs[c][g][n] = h[n];
  Ss[c][g] = S;
  __syncthreads();

  // ---------------- serial chunk combine: (channel, state) pairs ----------
  {
    const int gg = tid >> 4;
    const int n2 = tid & 15;
    const float An = -expf(A_log[(d0 + gg) * NST_ + n2]);
    float hin = 0.f;
#pragma unroll
    for (int cc = 0; cc < SC_C; ++cc) {
      const float tmp = Hs[cc][gg][n2];
      const float P = __expf(An * Ss[cc][gg]);
      Hs[cc][gg][n2] = hin;               // incoming state for chunk cc
      hin = tmp + P * hin;
    }
  }
  __syncthreads();

  // ---------------- pass 2: recompute with incoming state, emit y --------
#pragma unroll
  for (int n = 0; n < 16; ++n) h[n] = Hs[c][g][n];
  {
    size_t row = base + l0;
    float dtv = dt[row * DIN_ + d];
    float uv = u[row * DIN_ + d];
    float zv = xz[row * (2 * DIN_) + DIN_ + d];
    float Bv[16], Cv[16];
    *(float4*)&Bv[0]  = *(const float4*)(xdb + row * 64 + DTR_);
    *(float4*)&Bv[4]  = *(const float4*)(xdb + row * 64 + DTR_ + 4);
    *(float4*)&Bv[8]  = *(const float4*)(xdb + row * 64 + DTR_ + 8);
    *(float4*)&Bv[12] = *(const float4*)(xdb + row * 64 + DTR_ + 12);
    *(float4*)&Cv[0]  = *(const float4*)(xdb + row * 64 + DTR_ + 16);
    *(float4*)&Cv[4]  = *(const float4*)(xdb + row * 64 + DTR_ + 20);
    *(float4*)&Cv[8]  = *(const float4*)(xdb + row * 64 + DTR_ + 24);
    *(float4*)&Cv[12] = *(const float4*)(xdb + row * 64 + DTR_ + 28);
    for (int i = 0; i < SC_LEN; ++i) {
      float ndt = 0.f, nu = 0.f, nz = 0.f;
      float NB[16], NC[16];
      if (i + 1 < SC_LEN) {
        const size_t nrow = row + 1;
        ndt = dt[nrow * DIN_ + d];
        nu = u[nrow * DIN_ + d];
        nz = xz[nrow * (2 * DIN_) + DIN_ + d];
        *(float4*)&NB[0]  = *(const float4*)(xdb + nrow * 64 + DTR_);
        *(float4*)&NB[4]  = *(const float4*)(xdb + nrow * 64 + DTR_ + 4);
        *(float4*)&NB[8]  = *(const float4*)(xdb + nrow * 64 + DTR_ + 8);
        *(float4*)&NB[12] = *(const float4*)(xdb + nrow * 64 + DTR_ + 12);
        *(float4*)&NC[0]  = *(const float4*)(xdb + nrow * 64 + DTR_ + 16);
        *(float4*)&NC[4]  = *(const float4*)(xdb + nrow * 64 + DTR_ + 20);
        *(float4*)&NC[8]  = *(const float4*)(xdb + nrow * 64 + DTR_ + 24);
        *(float4*)&NC[12] = *(const float4*)(xdb + nrow * 64 + DTR_ + 28);
      }
      const float du = dtv * uv;
      float y = uv * Dpd;
#pragma unroll
      for (int n = 0; n < 16; ++n) {
        h[n] = __expf(dtv * A[n]) * h[n] + du * Bv[n];
        y = fmaf(h[n], Cv[n], y);
      }
      y *= zv / (1.f + __expf(-zv));
      ys[row * DIN_ + d] = y;
      dtv = ndt; uv = nu; zv = nz;
#pragma unroll
      for (int n = 0; n < 16; ++n) { Bv[n] = NB[n]; Cv[n] = NC[n]; }
      row += 1;
    }
  }
}

// ---------------------------------------------------------------------------
// Transpose tconv_w (O,I,3) -> (O, tap*512 + d).
// ---------------------------------------------------------------------------
__global__ __launch_bounds__(256) void twt_k(const float* __restrict__ in,
                                             float* __restrict__ out)
{
  const int i = blockIdx.x * 256 + threadIdx.x;
  if (i >= D_ * D_ * 3) return;
  const int o = i / (D_ * 3);
  const int rem = i - o * (D_ * 3);
  const int d = rem / 3;
  const int tap = rem - d * 3;
  out[(size_t)o * (D_ * 3) + tap * D_ + d] = in[i];
}

// ---------------------------------------------------------------------------
extern "C" void kernel_launch(void* const* d_in, const int* in_sizes, int n_in,
                              void* d_out, int out_size, void* d_ws, size_t ws_size,
                              hipStream_t stream)
{
  const float* x         = (const float*)d_in[0];
  const float* tconv_w   = (const float*)d_in[1];
  const float* tconv_b   = (const float*)d_in[2];
  const float* tnorm_w   = (const float*)d_in[3];
  const float* tnorm_b   = (const float*)d_in[4];
  const float* ln1_w     = (const float*)d_in[5];
  const float* ln1_b     = (const float*)d_in[6];
  const float* in_proj_w = (const float*)d_in[7];
  const float* conv_w    = (const float*)d_in[8];
  const float* conv_b    = (const float*)d_in[9];
  const float* x_proj_w  = (const float*)d_in[10];
  const float* dt_proj_w = (const float*)d_in[11];
  const float* dt_proj_b = (const float*)d_in[12];
  const float* A_log     = (const float*)d_in[13];
  const float* D_param   = (const float*)d_in[14];
  const float* out_proj_w= (const float*)d_in[15];
  const float* ln2_w     = (const float*)d_in[16];
  const float* ln2_b     = (const float*)d_in[17];
  const float* ffn_w1    = (const float*)d_in[18];
  const float* ffn_b1    = (const float*)d_in[19];
  const float* ffn_w2    = (const float*)d_in[20];
  const float* ffn_b2    = (const float*)d_in[21];

  float* h = (float*)d_out;
  const int M = B_ * L_;  // 8192

  float* ws    = (float*)d_ws;
  float* wTT   = ws;                          // 786432
  float* wsA   = wTT + 786432;                // M*512
  float* wsXZ  = wsA + (size_t)M * D_;        // M*2048
  float* wsU   = wsXZ + (size_t)M * 2 * DIN_; // M*1024 (u, ys in place)
  float* wsXDB = wsU + (size_t)M * DIN_;      // M*64
  float* wsDT  = wsXDB + (size_t)M * 64;      // M*1024 (dt, then ff)

  const dim3 blk(256);

  // temporal conv (GEMM + fused im2col) + LN(hc + x) -> h
  twt_k<<<dim3((D_ * D_ * 3 + 255) / 256), blk, 0, stream>>>(tconv_w, wTT);
  mgemm_k<1, 1, 128><<<dim3(D_ / 128, M / 128), blk, 0, stream>>>(
      x, wTT, tconv_b, wsA, M, D_, D_ * 3, 0, D_);
  ln_k<<<dim3(M), blk, 0, stream>>>(wsA, x, tnorm_w, tnorm_b, h);

  for (int i = 0; i < NB_; ++i) {
    const float* ipw = in_proj_w + (size_t)i * 2 * DIN_ * D_;
    const float* cw  = conv_w + (size_t)i * DIN_ * 4;
    const float* cb  = conv_b + (size_t)i * DIN_;
    const float* xpw = x_proj_w + (size_t)i * 64 * DIN_;
    const float* dtw = dt_proj_w + (size_t)i * DIN_ * DTR_;
    const float* dtb = dt_proj_b + (size_t)i * DIN_;
    const float* Al  = A_log + (size_t)i * DIN_ * NST_;
    const float* Dpp = D_param + (size_t)i * DIN_;
    const float* opw = out_proj_w + (size_t)i * D_ * DIN_;

    // xin = LN(h)
    ln_k<<<dim3(M), blk, 0, stream>>>(h, nullptr, ln1_w + i * D_, ln1_b + i * D_, wsA);
    // xz = xin @ in_proj^T
    mgemm_k<0, 0, 128><<<dim3(2 * DIN_ / 128, M / 128), blk, 0, stream>>>(
        wsA, ipw, nullptr, wsXZ, M, 2 * DIN_, D_, D_, 2 * DIN_);
    // u = silu(dwconv(u) + cb)
    dwconv_k<<<dim3(M * DIN_ / 256), blk, 0, stream>>>(wsXZ, cw, cb, wsU);
    // xdb = u @ x_proj^T   (N=64)
    mgemm_k<0, 0, 64><<<dim3(1, M / 128), blk, 0, stream>>>(
        wsU, xpw, nullptr, wsXDB, M, 64, DIN_, DIN_, 64);
    // dt = softplus(xdb[:, :32] @ dt_proj^T + dtb)   (K=32)
    mgemm_k<0, 3, 128><<<dim3(DIN_ / 128, M / 128), blk, 0, stream>>>(
        wsXDB, dtw, dtb, wsDT, M, DIN_, DTR_, 64, DIN_);
    // selective scan; ys overwrites u in place
    scan3_k<<<dim3(B_ * (DIN_ / SC_G)), dim3(512), 0, stream>>>(
        wsDT, wsU, wsXDB, wsXZ, Al, Dpp, wsU);
    // h += ys @ out_proj^T
    mgemm_k<0, 4, 128><<<dim3(D_ / 128, M / 128), blk, 0, stream>>>(
        wsU, opw, nullptr, h, M, D_, DIN_, DIN_, D_);
    // hn = LN(h); ff = gelu(hn @ w1^T + b1); h += ff @ w2^T + b2
    ln_k<<<dim3(M), blk, 0, stream>>>(h, nullptr, ln2_w + i * D_, ln2_b + i * D_, wsA);
    mgemm_k<0, 2, 128><<<dim3(FF_ / 128, M / 128), blk, 0, stream>>>(
        wsA, ffn_w1 + (size_t)i * FF_ * D_, ffn_b1 + (size_t)i * FF_, wsDT,
        M, FF_, D_, D_, FF_);
    mgemm_k<0, 5, 128><<<dim3(D_ / 128, M / 128), blk, 0, stream>>>(
        wsDT, ffn_w2 + (size_t)i * D_ * FF_, ffn_b2 + (size_t)i * D_, h,
        M, D_, FF_, FF_, D_);
  }
}

// Round 5
// 1500.456 us; speedup vs baseline: 4.2752x; 1.4300x over previous
//
#include <hip/hip_runtime.h>
#include <hip/hip_bf16.h>
#include <math.h>

#define B_ 8
#define L_ 1024
#define D_ 512
#define NB_ 4
#define DIN_ 1024
#define NST_ 16
#define DTR_ 32
#define FF_ 1024
#define EPS_LN 1e-5f
#define M_ (B_ * L_)

#define SC_G 32                 // channels per scan block
#define SC_C 16                 // L-chunks per scan block
#define SC_LEN (L_ / SC_C)      // 64 steps per chunk

typedef __attribute__((ext_vector_type(8))) short short8;
typedef __attribute__((ext_vector_type(4))) float f32x4;

static __device__ __forceinline__ ushort f2bf(float f) {
  union { float f; unsigned u; } v; v.f = f;
  unsigned r = v.u + 0x7FFFu + ((v.u >> 16) & 1u);
  return (ushort)(r >> 16);
}
static __device__ __forceinline__ float bf2f(ushort u) {
  union { unsigned u; float f; } v; v.u = ((unsigned)u) << 16;
  return v.f;
}

// ---------------------------------------------------------------------------
// bf16 MFMA GEMM:  C[m,n] = epi( sum_k A[m,k] * W[n,k] (+ bias[n]) )
// W bf16 (N,K) row-major. A bf16 (AF32=0) or fp32 (AF32=1, converted in stage).
// Tile 128 x BN, BK=32, 256 threads = 4 waves (2x2), wave tile 64 x BN/2.
// MODE 0: A[m*lda+k].  MODE 1: im2col of fp32 x (B,L,D), k=tap*512+d, pad 1.
// EPI: 0 store, 1 +bias, 2 +bias+gelu, 3 +bias+softplus, 4 C+=, 5 C+=+bias,
//      6 dual-out: n<1024 -> softplus(+bias) -> C (fp32, ldc 1024);
//                  1024<=n<1056 -> C2[m*32 + n-1024] (fp32); else skip.
// OUTB: store bf16 (EPI 0/1/2/3 only).
// LDS swizzle: 16B chunk slot j -> j ^ ((row>>1)&3)  (reads 2-way = free).
// ---------------------------------------------------------------------------
template <int MODE, int EPI, int BN, int AF32, int OUTB>
__global__ __launch_bounds__(256) void mgemm_k(
    const void* __restrict__ Ap, const ushort* __restrict__ W,
    const float* __restrict__ bias, void* __restrict__ Cp,
    float* __restrict__ C2, int M, int N, int K, int lda, int ldc)
{
  constexpr int FN = BN / 32;
  __shared__ ushort As[128 * 32];
  __shared__ ushort Bs[BN * 32];
  const int tid = threadIdx.x;
  const int lane = tid & 63;
  const int wid = tid >> 6;
  const int wm = (wid >> 1) * 64;
  const int wn = (wid & 1) * (BN / 2);
  const int bm = blockIdx.y * 128;
  const int bn = blockIdx.x * BN;
  const int fr = lane & 15;
  const int kq = lane >> 4;

  f32x4 acc[4][FN];
#pragma unroll
  for (int i = 0; i < 4; ++i)
#pragma unroll
    for (int j = 0; j < FN; ++j) acc[i][j] = (f32x4)0.f;

  for (int k0 = 0; k0 < K; k0 += 32) {
    // ---- stage A tile: 128 rows x 32 bf16, 4 chunks of 8 per row ----
#pragma unroll
    for (int it = 0; it < 2; ++it) {
      const int idx = tid + it * 256;
      const int row = idx >> 2;
      const int j = idx & 3;
      short8 s;
      if (AF32) {
        float4 v0, v1;
        if (MODE == 0) {
          const float* p = (const float*)Ap + (size_t)(bm + row) * lda + k0 + j * 8;
          v0 = *(const float4*)p; v1 = *(const float4*)(p + 4);
        } else {
          const int kk = k0 + j * 8;
          const int tap = kk >> 9;
          const int dcol = kk & 511;
          const int m = bm + row;
          const int l = (m & (L_ - 1)) + tap - 1;
          if (l >= 0 && l < L_) {
            const float* p = (const float*)Ap + (size_t)(m - (m & (L_ - 1)) + l) * D_ + dcol;
            v0 = *(const float4*)p; v1 = *(const float4*)(p + 4);
          } else {
            v0 = make_float4(0.f, 0.f, 0.f, 0.f); v1 = v0;
          }
        }
        s[0] = (short)f2bf(v0.x); s[1] = (short)f2bf(v0.y);
        s[2] = (short)f2bf(v0.z); s[3] = (short)f2bf(v0.w);
        s[4] = (short)f2bf(v1.x); s[5] = (short)f2bf(v1.y);
        s[6] = (short)f2bf(v1.z); s[7] = (short)f2bf(v1.w);
      } else {
        s = *(const short8*)((const ushort*)Ap + (size_t)(bm + row) * lda + k0 + j * 8);
      }
      *(short8*)&As[row * 32 + ((j ^ ((row >> 1) & 3)) << 3)] = s;
    }
    // ---- stage B tile: BN rows x 32 bf16 ----
#pragma unroll
    for (int it = 0; it < BN / 64; ++it) {
      const int idx = tid + it * 256;
      const int row = idx >> 2;
      const int j = idx & 3;
      short8 s = *(const short8*)(W + (size_t)(bn + row) * K + k0 + j * 8);
      *(short8*)&Bs[row * 32 + ((j ^ ((row >> 1) & 3)) << 3)] = s;
    }
    __syncthreads();
    short8 af[4], bfr[FN];
#pragma unroll
    for (int mi = 0; mi < 4; ++mi) {
      const int r = wm + mi * 16 + fr;
      af[mi] = *(const short8*)&As[r * 32 + ((kq ^ ((r >> 1) & 3)) << 3)];
    }
#pragma unroll
    for (int ni = 0; ni < FN; ++ni) {
      const int r = wn + ni * 16 + fr;
      bfr[ni] = *(const short8*)&Bs[r * 32 + ((kq ^ ((r >> 1) & 3)) << 3)];
    }
#pragma unroll
    for (int mi = 0; mi < 4; ++mi)
#pragma unroll
      for (int ni = 0; ni < FN; ++ni)
        acc[mi][ni] = __builtin_amdgcn_mfma_f32_16x16x32_bf16(
            af[mi], bfr[ni], acc[mi][ni], 0, 0, 0);
    __syncthreads();
  }

  // ---- epilogue: D layout col=lane&15, row=(lane>>4)*4+reg ----
#pragma unroll
  for (int mi = 0; mi < 4; ++mi) {
#pragma unroll
    for (int ni = 0; ni < FN; ++ni) {
#pragma unroll
      for (int r = 0; r < 4; ++r) {
        const int gm = bm + wm + mi * 16 + (lane >> 4) * 4 + r;
        const int gn = bn + wn + ni * 16 + fr;
        float v = acc[mi][ni][r];
        if (EPI == 6) {
          if (gn < DIN_) {
            v += bias[gn];
            v = (v > 20.f) ? v : log1pf(__expf(v));
            ((float*)Cp)[(size_t)gm * DIN_ + gn] = v;
          } else if (gn < DIN_ + 2 * NST_) {
            C2[(size_t)gm * (2 * NST_) + (gn - DIN_)] = v;
          }
        } else {
          if (EPI == 1 || EPI == 2 || EPI == 3 || EPI == 5) v += bias[gn];
          if (EPI == 2) v = 0.5f * v * (1.f + erff(v * 0.70710678118654752f));
          if (EPI == 3) v = (v > 20.f) ? v : log1pf(__expf(v));
          if (OUTB) {
            ((ushort*)Cp)[(size_t)gm * ldc + gn] = f2bf(v);
          } else {
            float* pc = (float*)Cp + (size_t)gm * ldc + gn;
            if (EPI == 4 || EPI == 5) v += *pc;
            *pc = v;
          }
        }
      }
    }
  }
}

// ---------------------------------------------------------------------------
// LayerNorm over last dim 512. INB: input bf16. OUTB: output bf16.
// res (fp32) optional.
// ---------------------------------------------------------------------------
template <int INB, int OUTB>
__global__ __launch_bounds__(256) void ln_k(
    const void* __restrict__ inp, const float* __restrict__ res,
    const float* __restrict__ w, const float* __restrict__ b,
    void* __restrict__ outp)
{
  const int row = blockIdx.x;
  const int t = threadIdx.x;
  float v0, v1;
  if (INB) {
    const ushort* p = (const ushort*)inp + (size_t)row * D_;
    v0 = bf2f(p[t]); v1 = bf2f(p[t + 256]);
  } else {
    const float* p = (const float*)inp + (size_t)row * D_;
    v0 = p[t]; v1 = p[t + 256];
  }
  if (res) {
    const float* r = res + (size_t)row * D_;
    v0 += r[t]; v1 += r[t + 256];
  }
  float s = v0 + v1;
  float sq = v0 * v0 + v1 * v1;
#pragma unroll
  for (int m = 1; m < 64; m <<= 1) {
    s += __shfl_xor(s, m, 64);
    sq += __shfl_xor(sq, m, 64);
  }
  __shared__ float ss[4], qq[4];
  const int wid = t >> 6;
  if ((t & 63) == 0) { ss[wid] = s; qq[wid] = sq; }
  __syncthreads();
  s = ss[0] + ss[1] + ss[2] + ss[3];
  sq = qq[0] + qq[1] + qq[2] + qq[3];
  const float mu = s * (1.f / (float)D_);
  const float var = sq * (1.f / (float)D_) - mu * mu;
  const float rs = rsqrtf(var + EPS_LN);
  const float o0 = (v0 - mu) * rs * w[t] + b[t];
  const float o1 = (v1 - mu) * rs * w[t + 256] + b[t + 256];
  if (OUTB) {
    ushort* o = (ushort*)outp + (size_t)row * D_;
    o[t] = f2bf(o0); o[t + 256] = f2bf(o1);
  } else {
    float* o = (float*)outp + (size_t)row * D_;
    o[t] = o0; o[t + 256] = o1;
  }
}

// ---------------------------------------------------------------------------
// Depthwise causal conv (k=4, pad 3) over u-half of xz (bf16), +bias, +silu.
// ---------------------------------------------------------------------------
__global__ __launch_bounds__(256) void dwconv_k(
    const ushort* __restrict__ xz, const float* __restrict__ cw,
    const float* __restrict__ cb, ushort* __restrict__ u)
{
  const int idx = blockIdx.x * 256 + threadIdx.x;
  const int c = idx & (DIN_ - 1);
  const int bl = idx >> 10;
  const int l = bl & (L_ - 1);
  const int b0 = bl - l;
  float s = cb[c];
#pragma unroll
  for (int k = 0; k < 4; ++k) {
    const int ll = l + k - 3;
    if (ll >= 0)
      s = fmaf(bf2f(xz[(size_t)(b0 + ll) * (2 * DIN_) + c]), cw[c * 4 + k], s);
  }
  s = s / (1.f + __expf(-s));
  u[idx] = f2bf(s);
}

// ---------------------------------------------------------------------------
// Coalesced chunked selective scan (bf16 u in / ys out in-place, fp32 dt/BC).
// Block = (b, 32-channel group). 512 thr = 32 channels x 16 chunks (64 steps).
// ---------------------------------------------------------------------------
__global__ __launch_bounds__(512) void scan4_k(
    const float* __restrict__ dt, ushort* u,
    const float* __restrict__ BC, const ushort* __restrict__ xz,
    const float* __restrict__ A_log, const float* __restrict__ Dp)
{
  const int tid = threadIdx.x;
  const int g = tid & (SC_G - 1);
  const int c = tid >> 5;
  const int b = blockIdx.x >> 5;
  const int d0 = (blockIdx.x & 31) * SC_G;
  const int d = d0 + g;

  __shared__ float Hs[SC_C][SC_G][NST_ + 1];
  __shared__ float Ss[SC_C][SC_G];

  float A[16];
#pragma unroll
  for (int n = 0; n < 16; ++n) A[n] = -expf(A_log[d * NST_ + n]);
  const float Dpd = Dp[d];

  const size_t base = (size_t)b * L_;
  const int l0 = c * SC_LEN;

  // ---------------- pass 1: local scan + decay sum ----------------
  float h[16];
#pragma unroll
  for (int n = 0; n < 16; ++n) h[n] = 0.f;
  float S = 0.f;
  {
    size_t row = base + l0;
    float dtv = dt[row * DIN_ + d];
    float uv = bf2f(u[row * DIN_ + d]);
    float Bv[16];
    *(float4*)&Bv[0]  = *(const float4*)(BC + row * 32);
    *(float4*)&Bv[4]  = *(const float4*)(BC + row * 32 + 4);
    *(float4*)&Bv[8]  = *(const float4*)(BC + row * 32 + 8);
    *(float4*)&Bv[12] = *(const float4*)(BC + row * 32 + 12);
    for (int i = 0; i < SC_LEN; ++i) {
      float ndt = 0.f, nu = 0.f;
      float NBv[16];
      if (i + 1 < SC_LEN) {
        const size_t nrow = row + 1;
        ndt = dt[nrow * DIN_ + d];
        nu = bf2f(u[nrow * DIN_ + d]);
        *(float4*)&NBv[0]  = *(const float4*)(BC + nrow * 32);
        *(float4*)&NBv[4]  = *(const float4*)(BC + nrow * 32 + 4);
        *(float4*)&NBv[8]  = *(const float4*)(BC + nrow * 32 + 8);
        *(float4*)&NBv[12] = *(const float4*)(BC + nrow * 32 + 12);
      }
      S += dtv;
      const float du = dtv * uv;
#pragma unroll
      for (int n = 0; n < 16; ++n)
        h[n] = __expf(dtv * A[n]) * h[n] + du * Bv[n];
      dtv = ndt; uv = nu;
#pragma unroll
      for (int n = 0; n < 16; ++n) Bv[n] = NBv[n];
      row += 1;
    }
  }
#pragma unroll
  for (int n = 0; n < 16; ++n) Hs[c][g][n] = h[n];
  Ss[c][g] = S;
  __syncthreads();

  // ---------------- serial chunk combine ----------------
  {
    const int gg = tid >> 4;
    const int n2 = tid & 15;
    const float An = -expf(A_log[(d0 + gg) * NST_ + n2]);
    float hin = 0.f;
#pragma unroll
    for (int cc = 0; cc < SC_C; ++cc) {
      const float tmp = Hs[cc][gg][n2];
      const float P = __expf(An * Ss[cc][gg]);
      Hs[cc][gg][n2] = hin;
      hin = tmp + P * hin;
    }
  }
  __syncthreads();

  // ---------------- pass 2: recompute + emit y ----------------
#pragma unroll
  for (int n = 0; n < 16; ++n) h[n] = Hs[c][g][n];
  {
    size_t row = base + l0;
    float dtv = dt[row * DIN_ + d];
    float uv = bf2f(u[row * DIN_ + d]);
    float zv = bf2f(xz[row * (2 * DIN_) + DIN_ + d]);
    float Bv[16], Cv[16];
    *(float4*)&Bv[0]  = *(const float4*)(BC + row * 32);
    *(float4*)&Bv[4]  = *(const float4*)(BC + row * 32 + 4);
    *(float4*)&Bv[8]  = *(const float4*)(BC + row * 32 + 8);
    *(float4*)&Bv[12] = *(const float4*)(BC + row * 32 + 12);
    *(float4*)&Cv[0]  = *(const float4*)(BC + row * 32 + 16);
    *(float4*)&Cv[4]  = *(const float4*)(BC + row * 32 + 20);
    *(float4*)&Cv[8]  = *(const float4*)(BC + row * 32 + 24);
    *(float4*)&Cv[12] = *(const float4*)(BC + row * 32 + 28);
    for (int i = 0; i < SC_LEN; ++i) {
      float ndt = 0.f, nu = 0.f, nz = 0.f;
      float NBv[16], NCv[16];
      if (i + 1 < SC_LEN) {
        const size_t nrow = row + 1;
        ndt = dt[nrow * DIN_ + d];
        nu = bf2f(u[nrow * DIN_ + d]);
        nz = bf2f(xz[nrow * (2 * DIN_) + DIN_ + d]);
        *(float4*)&NBv[0]  = *(const float4*)(BC + nrow * 32);
        *(float4*)&NBv[4]  = *(const float4*)(BC + nrow * 32 + 4);
        *(float4*)&NBv[8]  = *(const float4*)(BC + nrow * 32 + 8);
        *(float4*)&NBv[12] = *(const float4*)(BC + nrow * 32 + 12);
        *(float4*)&NCv[0]  = *(const float4*)(BC + nrow * 32 + 16);
        *(float4*)&NCv[4]  = *(const float4*)(BC + nrow * 32 + 20);
        *(float4*)&NCv[8]  = *(const float4*)(BC + nrow * 32 + 24);
        *(float4*)&NCv[12] = *(const float4*)(BC + nrow * 32 + 28);
      }
      const float du = dtv * uv;
      float y = uv * Dpd;
#pragma unroll
      for (int n = 0; n < 16; ++n) {
        h[n] = __expf(dtv * A[n]) * h[n] + du * Bv[n];
        y = fmaf(h[n], Cv[n], y);
      }
      y *= zv / (1.f + __expf(-zv));
      u[row * DIN_ + d] = f2bf(y);
      dtv = ndt; uv = nu; zv = nz;
#pragma unroll
      for (int n = 0; n < 16; ++n) { Bv[n] = NBv[n]; Cv[n] = NCv[n]; }
      row += 1;
    }
  }
}

// ---------------------------------------------------------------------------
// Small helper kernels
// ---------------------------------------------------------------------------
__global__ __launch_bounds__(256) void cvt_k(const float* __restrict__ in,
                                             ushort* __restrict__ out, int n8)
{
  const int i = blockIdx.x * 256 + threadIdx.x;
  if (i >= n8) return;
  const float4 a = *(const float4*)(in + (size_t)i * 8);
  const float4 b = *(const float4*)(in + (size_t)i * 8 + 4);
  short8 s;
  s[0] = (short)f2bf(a.x); s[1] = (short)f2bf(a.y);
  s[2] = (short)f2bf(a.z); s[3] = (short)f2bf(a.w);
  s[4] = (short)f2bf(b.x); s[5] = (short)f2bf(b.y);
  s[6] = (short)f2bf(b.z); s[7] = (short)f2bf(b.w);
  *(short8*)(out + (size_t)i * 8) = s;
}

// tconv_w (O,I,3) -> bf16 (O, tap*512 + d)
__global__ __launch_bounds__(256) void twt_k(const float* __restrict__ in,
                                             ushort* __restrict__ out)
{
  const int i = blockIdx.x * 256 + threadIdx.x;
  if (i >= D_ * D_ * 3) return;
  const int o = i / (D_ * 3);
  const int rem = i - o * (D_ * 3);
  const int d = rem / 3;
  const int tap = rem - d * 3;
  out[(size_t)o * (D_ * 3) + tap * D_ + d] = f2bf(in[i]);
}

// x_proj_w[0:32] (32,1024) -> bf16 transpose (1024,32)
__global__ __launch_bounds__(256) void xpT_k(const float* __restrict__ xpw,
                                             ushort* __restrict__ out)
{
  const int i = blockIdx.x * 256 + threadIdx.x;
  if (i >= DIN_ * DTR_) return;
  const int k = i >> 5;      // 0..1023
  const int r = i & 31;      // 0..31
  out[i] = f2bf(xpw[(size_t)r * DIN_ + k]);
}

// Wbig (1088,1024) bf16 = [Wcomb fp32 (1024); x_proj_w[32:64] (32); zeros(32)]
__global__ __launch_bounds__(256) void pack_k(const float* __restrict__ wc,
                                              const float* __restrict__ xpw,
                                              ushort* __restrict__ wbig)
{
  const int i = blockIdx.x * 256 + threadIdx.x;
  if (i >= 1088 * 1024) return;
  const int r = i >> 10;
  const int k = i & 1023;
  float v;
  if (r < 1024) v = wc[i];
  else if (r < 1056) v = xpw[(size_t)(DTR_ + r - 1024) * DIN_ + k];
  else v = 0.f;
  wbig[i] = f2bf(v);
}

// ---------------------------------------------------------------------------
extern "C" void kernel_launch(void* const* d_in, const int* in_sizes, int n_in,
                              void* d_out, int out_size, void* d_ws, size_t ws_size,
                              hipStream_t stream)
{
  const float* x         = (const float*)d_in[0];
  const float* tconv_w   = (const float*)d_in[1];
  const float* tconv_b   = (const float*)d_in[2];
  const float* tnorm_w   = (const float*)d_in[3];
  const float* tnorm_b   = (const float*)d_in[4];
  const float* ln1_w     = (const float*)d_in[5];
  const float* ln1_b     = (const float*)d_in[6];
  const float* in_proj_w = (const float*)d_in[7];
  const float* conv_w    = (const float*)d_in[8];
  const float* conv_b    = (const float*)d_in[9];
  const float* x_proj_w  = (const float*)d_in[10];
  const float* dt_proj_w = (const float*)d_in[11];
  const float* dt_proj_b = (const float*)d_in[12];
  const float* A_log     = (const float*)d_in[13];
  const float* D_param   = (const float*)d_in[14];
  const float* out_proj_w= (const float*)d_in[15];
  const float* ln2_w     = (const float*)d_in[16];
  const float* ln2_b     = (const float*)d_in[17];
  const float* ffn_w1    = (const float*)d_in[18];
  const float* ffn_b1    = (const float*)d_in[19];
  const float* ffn_w2    = (const float*)d_in[20];
  const float* ffn_b2    = (const float*)d_in[21];

  float* h = (float*)d_out;

  // ---- workspace layout (all 16B-aligned sizes) ----
  char* p = (char*)d_ws;
  ushort* wTT  = (ushort*)p; p += (size_t)512 * 1536 * 2;
  ushort* wIP  = (ushort*)p; p += (size_t)4 * 2048 * 512 * 2;
  ushort* wOP  = (ushort*)p; p += (size_t)4 * 512 * 1024 * 2;
  ushort* wF1  = (ushort*)p; p += (size_t)4 * 1024 * 512 * 2;
  ushort* wF2  = (ushort*)p; p += (size_t)4 * 512 * 1024 * 2;
  ushort* xpwT = (ushort*)p; p += (size_t)4 * 1024 * 32 * 2;
  ushort* wBig = (ushort*)p; p += (size_t)4 * 1088 * 1024 * 2;
  float*  wcT  = (float*)p;  p += (size_t)1024 * 1024 * 4;
  ushort* xin  = (ushort*)p; p += (size_t)M_ * 512 * 2;    // hc / xin / hn
  ushort* xzb  = (ushort*)p; p += (size_t)M_ * 2048 * 2;
  ushort* ubuf = (ushort*)p; p += (size_t)M_ * 1024 * 2;   // u, ys in place
  float*  bc   = (float*)p;  p += (size_t)M_ * 32 * 4;
  float*  dtb  = (float*)p;  p += (size_t)M_ * 1024 * 4;
  ushort* ff   = (ushort*)p; p += (size_t)M_ * 1024 * 2;

  const dim3 blk(256);

  // ---- preprocessing: weights -> bf16, Wcomb = dt_proj_w @ x_proj_w[0:32] ----
  cvt_k<<<dim3(4 * 2048 * 512 / 8 / 256), blk, 0, stream>>>(in_proj_w, wIP, 4 * 2048 * 512 / 8);
  cvt_k<<<dim3(4 * 512 * 1024 / 8 / 256), blk, 0, stream>>>(out_proj_w, wOP, 4 * 512 * 1024 / 8);
  cvt_k<<<dim3(4 * 1024 * 512 / 8 / 256), blk, 0, stream>>>(ffn_w1, wF1, 4 * 1024 * 512 / 8);
  cvt_k<<<dim3(4 * 512 * 1024 / 8 / 256), blk, 0, stream>>>(ffn_w2, wF2, 4 * 512 * 1024 / 8);
  twt_k<<<dim3((D_ * D_ * 3 + 255) / 256), blk, 0, stream>>>(tconv_w, wTT);
  for (int i = 0; i < NB_; ++i)
    xpT_k<<<dim3(DIN_ * DTR_ / 256), blk, 0, stream>>>(
        x_proj_w + (size_t)i * 64 * DIN_, xpwT + (size_t)i * DIN_ * DTR_);
  for (int i = 0; i < NB_; ++i) {
    mgemm_k<0, 0, 128, 1, 0><<<dim3(8, 8), blk, 0, stream>>>(
        dt_proj_w + (size_t)i * DIN_ * DTR_, xpwT + (size_t)i * DIN_ * DTR_,
        nullptr, wcT, nullptr, 1024, 1024, 32, 32, 1024);
    pack_k<<<dim3(1088 * 1024 / 256), blk, 0, stream>>>(
        wcT, x_proj_w + (size_t)i * 64 * DIN_, wBig + (size_t)i * 1088 * 1024);
  }

  // ---- temporal conv (GEMM + fused im2col) + LN(hc + x) -> h ----
  mgemm_k<1, 1, 64, 1, 1><<<dim3(8, 64), blk, 0, stream>>>(
      x, wTT, tconv_b, xin, nullptr, M_, 512, 1536, 0, 512);
  ln_k<1, 0><<<dim3(M_), blk, 0, stream>>>(xin, x, tnorm_w, tnorm_b, h);

  for (int i = 0; i < NB_; ++i) {
    // xin = LN(h)  (bf16)
    ln_k<0, 1><<<dim3(M_), blk, 0, stream>>>(h, nullptr, ln1_w + i * D_, ln1_b + i * D_, xin);
    // xz = xin @ in_proj^T  (bf16)
    mgemm_k<0, 0, 128, 0, 1><<<dim3(16, 64), blk, 0, stream>>>(
        xin, wIP + (size_t)i * 2048 * 512, nullptr, xzb, nullptr,
        M_, 2048, 512, 512, 2048);
    // u = silu(dwconv(xz_u) + cb)  (bf16)
    dwconv_k<<<dim3(M_ * DIN_ / 256), blk, 0, stream>>>(
        xzb, conv_w + (size_t)i * DIN_ * 4, conv_b + (size_t)i * DIN_, ubuf);
    // dt (softplus, fp32) + B/C (fp32) in one GEMM vs Wbig
    mgemm_k<0, 6, 64, 0, 0><<<dim3(17, 64), blk, 0, stream>>>(
        ubuf, wBig + (size_t)i * 1088 * 1024, dt_proj_b + (size_t)i * DIN_,
        dtb, bc, M_, 1088, 1024, 1024, 1024);
    // selective scan; ys overwrites u in place (bf16)
    scan4_k<<<dim3(B_ * (DIN_ / SC_G)), dim3(512), 0, stream>>>(
        dtb, ubuf, bc, xzb, A_log + (size_t)i * DIN_ * NST_, D_param + (size_t)i * DIN_);
    // h += ys @ out_proj^T
    mgemm_k<0, 4, 64, 0, 0><<<dim3(8, 64), blk, 0, stream>>>(
        ubuf, wOP + (size_t)i * 512 * 1024, nullptr, h, nullptr,
        M_, 512, 1024, 1024, 512);
    // hn = LN(h) (bf16); ff = gelu(hn @ w1^T + b1) (bf16); h += ff @ w2^T + b2
    ln_k<0, 1><<<dim3(M_), blk, 0, stream>>>(h, nullptr, ln2_w + i * D_, ln2_b + i * D_, xin);
    mgemm_k<0, 2, 64, 0, 1><<<dim3(16, 64), blk, 0, stream>>>(
        xin, wF1 + (size_t)i * 1024 * 512, ffn_b1 + (size_t)i * FF_, ff, nullptr,
        M_, 1024, 512, 512, 1024);
    mgemm_k<0, 5, 64, 0, 0><<<dim3(8, 64), blk, 0, stream>>>(
        ff, wF2 + (size_t)i * 512 * 1024, ffn_b2 + (size_t)i * D_, h, nullptr,
        M_, 512, 1024, 1024, 512);
  }
}

// Round 6
// 1473.680 us; speedup vs baseline: 4.3529x; 1.0182x over previous
//
#include <hip/hip_runtime.h>
#include <hip/hip_bf16.h>
#include <math.h>

#define B_ 8
#define L_ 1024
#define D_ 512
#define NB_ 4
#define DIN_ 1024
#define NST_ 16
#define DTR_ 32
#define FF_ 1024
#define EPS_LN 1e-5f
#define M_ (B_ * L_)

#define SC_G 16                 // channels per scan block
#define SC_C 32                 // L-chunks per scan block
#define SC_LEN (L_ / SC_C)      // 32 steps per chunk

typedef __attribute__((ext_vector_type(8))) short short8;
typedef __attribute__((ext_vector_type(4))) float f32x4;

static __device__ __forceinline__ ushort f2bf(float f) {
  union { float f; unsigned u; } v; v.f = f;
  unsigned r = v.u + 0x7FFFu + ((v.u >> 16) & 1u);
  return (ushort)(r >> 16);
}
static __device__ __forceinline__ float bf2f(ushort u) {
  union { unsigned u; float f; } v; v.u = ((unsigned)u) << 16;
  return v.f;
}

// ---------------------------------------------------------------------------
// bf16 MFMA GEMM:  C[m,n] = epi( sum_k A[m,k] * W[n,k] (+ bias[n]) )
// W bf16 (N,K) row-major. A bf16 (AF32=0) or fp32 (AF32=1, converted in stage).
// Tile 128 x BN, BK=32, 256 threads = 4 waves (2x2), wave tile 64 x BN/2.
// MODE 0: A[m*lda+k].  MODE 1: im2col of fp32 x (B,L,D), k=tap*512+d, pad 1.
// EPI: 0 store, 1 +bias, 2 +bias+gelu, 3 +bias+softplus, 4 C+=, 5 C+=+bias,
//      6 dual-out: n<1024 -> softplus(+bias) -> C (fp32, ldc 1024);
//                  1024<=n<1056 -> C2[m*32 + n-1024] (fp32); else skip.
// OUTB: store bf16 (EPI 0/1/2/3 only).
// ---------------------------------------------------------------------------
template <int MODE, int EPI, int BN, int AF32, int OUTB>
__global__ __launch_bounds__(256) void mgemm_k(
    const void* __restrict__ Ap, const ushort* __restrict__ W,
    const float* __restrict__ bias, void* __restrict__ Cp,
    float* __restrict__ C2, int M, int N, int K, int lda, int ldc)
{
  constexpr int FN = BN / 32;
  __shared__ ushort As[128 * 32];
  __shared__ ushort Bs[BN * 32];
  const int tid = threadIdx.x;
  const int lane = tid & 63;
  const int wid = tid >> 6;
  const int wm = (wid >> 1) * 64;
  const int wn = (wid & 1) * (BN / 2);
  const int bm = blockIdx.y * 128;
  const int bn = blockIdx.x * BN;
  const int fr = lane & 15;
  const int kq = lane >> 4;

  f32x4 acc[4][FN];
#pragma unroll
  for (int i = 0; i < 4; ++i)
#pragma unroll
    for (int j = 0; j < FN; ++j) acc[i][j] = (f32x4)0.f;

  for (int k0 = 0; k0 < K; k0 += 32) {
#pragma unroll
    for (int it = 0; it < 2; ++it) {
      const int idx = tid + it * 256;
      const int row = idx >> 2;
      const int j = idx & 3;
      short8 s;
      if (AF32) {
        float4 v0, v1;
        if (MODE == 0) {
          const float* p = (const float*)Ap + (size_t)(bm + row) * lda + k0 + j * 8;
          v0 = *(const float4*)p; v1 = *(const float4*)(p + 4);
        } else {
          const int kk = k0 + j * 8;
          const int tap = kk >> 9;
          const int dcol = kk & 511;
          const int m = bm + row;
          const int l = (m & (L_ - 1)) + tap - 1;
          if (l >= 0 && l < L_) {
            const float* p = (const float*)Ap + (size_t)(m - (m & (L_ - 1)) + l) * D_ + dcol;
            v0 = *(const float4*)p; v1 = *(const float4*)(p + 4);
          } else {
            v0 = make_float4(0.f, 0.f, 0.f, 0.f); v1 = v0;
          }
        }
        s[0] = (short)f2bf(v0.x); s[1] = (short)f2bf(v0.y);
        s[2] = (short)f2bf(v0.z); s[3] = (short)f2bf(v0.w);
        s[4] = (short)f2bf(v1.x); s[5] = (short)f2bf(v1.y);
        s[6] = (short)f2bf(v1.z); s[7] = (short)f2bf(v1.w);
      } else {
        s = *(const short8*)((const ushort*)Ap + (size_t)(bm + row) * lda + k0 + j * 8);
      }
      *(short8*)&As[row * 32 + ((j ^ ((row >> 1) & 3)) << 3)] = s;
    }
#pragma unroll
    for (int it = 0; it < BN / 64; ++it) {
      const int idx = tid + it * 256;
      const int row = idx >> 2;
      const int j = idx & 3;
      short8 s = *(const short8*)(W + (size_t)(bn + row) * K + k0 + j * 8);
      *(short8*)&Bs[row * 32 + ((j ^ ((row >> 1) & 3)) << 3)] = s;
    }
    __syncthreads();
    short8 af[4], bfr[FN];
#pragma unroll
    for (int mi = 0; mi < 4; ++mi) {
      const int r = wm + mi * 16 + fr;
      af[mi] = *(const short8*)&As[r * 32 + ((kq ^ ((r >> 1) & 3)) << 3)];
    }
#pragma unroll
    for (int ni = 0; ni < FN; ++ni) {
      const int r = wn + ni * 16 + fr;
      bfr[ni] = *(const short8*)&Bs[r * 32 + ((kq ^ ((r >> 1) & 3)) << 3)];
    }
#pragma unroll
    for (int mi = 0; mi < 4; ++mi)
#pragma unroll
      for (int ni = 0; ni < FN; ++ni)
        acc[mi][ni] = __builtin_amdgcn_mfma_f32_16x16x32_bf16(
            af[mi], bfr[ni], acc[mi][ni], 0, 0, 0);
    __syncthreads();
  }

#pragma unroll
  for (int mi = 0; mi < 4; ++mi) {
#pragma unroll
    for (int ni = 0; ni < FN; ++ni) {
#pragma unroll
      for (int r = 0; r < 4; ++r) {
        const int gm = bm + wm + mi * 16 + (lane >> 4) * 4 + r;
        const int gn = bn + wn + ni * 16 + fr;
        float v = acc[mi][ni][r];
        if (EPI == 6) {
          if (gn < DIN_) {
            v += bias[gn];
            v = (v > 20.f) ? v : log1pf(__expf(v));
            ((float*)Cp)[(size_t)gm * DIN_ + gn] = v;
          } else if (gn < DIN_ + 2 * NST_) {
            C2[(size_t)gm * (2 * NST_) + (gn - DIN_)] = v;
          }
        } else {
          if (EPI == 1 || EPI == 2 || EPI == 3 || EPI == 5) v += bias[gn];
          if (EPI == 2) v = 0.5f * v * (1.f + erff(v * 0.70710678118654752f));
          if (EPI == 3) v = (v > 20.f) ? v : log1pf(__expf(v));
          if (OUTB) {
            ((ushort*)Cp)[(size_t)gm * ldc + gn] = f2bf(v);
          } else {
            float* pc = (float*)Cp + (size_t)gm * ldc + gn;
            if (EPI == 4 || EPI == 5) v += *pc;
            *pc = v;
          }
        }
      }
    }
  }
}

// ---------------------------------------------------------------------------
// LayerNorm over last dim 512. INB: input bf16. OUTB: output bf16.
// ---------------------------------------------------------------------------
template <int INB, int OUTB>
__global__ __launch_bounds__(256) void ln_k(
    const void* __restrict__ inp, const float* __restrict__ res,
    const float* __restrict__ w, const float* __restrict__ b,
    void* __restrict__ outp)
{
  const int row = blockIdx.x;
  const int t = threadIdx.x;
  float v0, v1;
  if (INB) {
    const ushort* p = (const ushort*)inp + (size_t)row * D_;
    v0 = bf2f(p[t]); v1 = bf2f(p[t + 256]);
  } else {
    const float* p = (const float*)inp + (size_t)row * D_;
    v0 = p[t]; v1 = p[t + 256];
  }
  if (res) {
    const float* r = res + (size_t)row * D_;
    v0 += r[t]; v1 += r[t + 256];
  }
  float s = v0 + v1;
  float sq = v0 * v0 + v1 * v1;
#pragma unroll
  for (int m = 1; m < 64; m <<= 1) {
    s += __shfl_xor(s, m, 64);
    sq += __shfl_xor(sq, m, 64);
  }
  __shared__ float ss[4], qq[4];
  const int wid = t >> 6;
  if ((t & 63) == 0) { ss[wid] = s; qq[wid] = sq; }
  __syncthreads();
  s = ss[0] + ss[1] + ss[2] + ss[3];
  sq = qq[0] + qq[1] + qq[2] + qq[3];
  const float mu = s * (1.f / (float)D_);
  const float var = sq * (1.f / (float)D_) - mu * mu;
  const float rs = rsqrtf(var + EPS_LN);
  const float o0 = (v0 - mu) * rs * w[t] + b[t];
  const float o1 = (v1 - mu) * rs * w[t + 256] + b[t + 256];
  if (OUTB) {
    ushort* o = (ushort*)outp + (size_t)row * D_;
    o[t] = f2bf(o0); o[t + 256] = f2bf(o1);
  } else {
    float* o = (float*)outp + (size_t)row * D_;
    o[t] = o0; o[t + 256] = o1;
  }
}

// ---------------------------------------------------------------------------
// Depthwise causal conv (k=4, pad 3), vectorized 8 channels/thread.
// ---------------------------------------------------------------------------
__global__ __launch_bounds__(256) void dwconv_k(
    const ushort* __restrict__ xz, const float* __restrict__ cw,
    const float* __restrict__ cb, ushort* __restrict__ u)
{
  const int idx = blockIdx.x * 256 + threadIdx.x;   // M_*DIN_/8 threads
  const int c8 = idx & (DIN_ / 8 - 1);
  const int bl = idx >> 7;
  const int l = bl & (L_ - 1);
  const int b0 = bl - l;
  const int c0 = c8 * 8;
  float s[8], w[8][4];
#pragma unroll
  for (int j = 0; j < 8; ++j) {
    s[j] = cb[c0 + j];
    const float4 wv = *(const float4*)(cw + (c0 + j) * 4);
    w[j][0] = wv.x; w[j][1] = wv.y; w[j][2] = wv.z; w[j][3] = wv.w;
  }
#pragma unroll
  for (int k = 0; k < 4; ++k) {
    const int ll = l + k - 3;
    if (ll >= 0) {
      const short8 v = *(const short8*)(xz + (size_t)(b0 + ll) * (2 * DIN_) + c0);
#pragma unroll
      for (int j = 0; j < 8; ++j)
        s[j] = fmaf(bf2f((ushort)v[j]), w[j][k], s[j]);
    }
  }
  short8 o;
#pragma unroll
  for (int j = 0; j < 8; ++j) {
    const float t = s[j] / (1.f + __expf(-s[j]));
    o[j] = (short)f2bf(t);
  }
  *(short8*)(u + (size_t)idx * 8) = o;
}

// ---------------------------------------------------------------------------
// Selective scan helpers: dA[n] = exp(dt*A[n]).
// FAST path exploits A[n] = (n+1)*A[0] (mamba's A_log=log(1..N)): one exp +
// 15 full-rate muls instead of 16 quarter-rate exps. Verified at runtime.
// ---------------------------------------------------------------------------
template <bool FAST>
static __device__ __forceinline__ void dAcalc(float dtv, float A0,
                                              const float* A, float* dA)
{
  if (FAST) {
    const float e = __expf(dtv * A0);
    dA[0] = e;
#pragma unroll
    for (int n = 1; n < 16; ++n) dA[n] = dA[n - 1] * e;
  } else {
#pragma unroll
    for (int n = 0; n < 16; ++n) dA[n] = __expf(dtv * A[n]);
  }
}

template <bool FAST>
static __device__ __forceinline__ void scan_run(
    const float* __restrict__ dt, ushort* __restrict__ u,
    const float* __restrict__ BC, const ushort* __restrict__ xz,
    const float* __restrict__ A_log,
    const float* A, const float A0, const float Dpd,
    float (*Hs)[SC_G][NST_ + 1], float (*Ss)[SC_G],
    const int tid, const int g, const int c, const int d0, const int d,
    const size_t base)
{
  const int l0 = c * SC_LEN;
  float h[16];
#pragma unroll
  for (int n = 0; n < 16; ++n) h[n] = 0.f;
  float S = 0.f;

  // ---------------- pass 1: local scan + decay sum ----------------
  {
    size_t row = base + l0;
    float dtv = dt[row * DIN_ + d];
    float uv = bf2f(u[row * DIN_ + d]);
    float Bv[16];
    *(float4*)&Bv[0]  = *(const float4*)(BC + row * 32);
    *(float4*)&Bv[4]  = *(const float4*)(BC + row * 32 + 4);
    *(float4*)&Bv[8]  = *(const float4*)(BC + row * 32 + 8);
    *(float4*)&Bv[12] = *(const float4*)(BC + row * 32 + 12);
    for (int i = 0; i < SC_LEN; ++i) {
      float ndt = 0.f, nu = 0.f;
      float NBv[16];
      if (i + 1 < SC_LEN) {
        const size_t nrow = row + 1;
        ndt = dt[nrow * DIN_ + d];
        nu = bf2f(u[nrow * DIN_ + d]);
        *(float4*)&NBv[0]  = *(const float4*)(BC + nrow * 32);
        *(float4*)&NBv[4]  = *(const float4*)(BC + nrow * 32 + 4);
        *(float4*)&NBv[8]  = *(const float4*)(BC + nrow * 32 + 8);
        *(float4*)&NBv[12] = *(const float4*)(BC + nrow * 32 + 12);
      }
      S += dtv;
      const float du = dtv * uv;
      float dA[16];
      dAcalc<FAST>(dtv, A0, A, dA);
#pragma unroll
      for (int n = 0; n < 16; ++n)
        h[n] = fmaf(dA[n], h[n], du * Bv[n]);
      dtv = ndt; uv = nu;
#pragma unroll
      for (int n = 0; n < 16; ++n) Bv[n] = NBv[n];
      row += 1;
    }
  }
#pragma unroll
  for (int n = 0; n < 16; ++n) Hs[c][g][n] = h[n];
  Ss[c][g] = S;
  __syncthreads();

  // ---------------- serial chunk combine ((channel,state) pairs) ----------
  if (tid < SC_G * NST_) {
    const int gg = tid >> 4;
    const int n2 = tid & 15;
    const float An = -expf(A_log[(d0 + gg) * NST_ + n2]);
    float hin = 0.f;
#pragma unroll
    for (int cc = 0; cc < SC_C; ++cc) {
      const float tmp = Hs[cc][gg][n2];
      const float P = __expf(An * Ss[cc][gg]);
      Hs[cc][gg][n2] = hin;
      hin = tmp + P * hin;
    }
  }
  __syncthreads();

  // ---------------- pass 2: recompute with incoming state, emit y ---------
#pragma unroll
  for (int n = 0; n < 16; ++n) h[n] = Hs[c][g][n];
  {
    size_t row = base + l0;
    float dtv = dt[row * DIN_ + d];
    float uv = bf2f(u[row * DIN_ + d]);
    float zv = bf2f(xz[row * (2 * DIN_) + DIN_ + d]);
    float Bv[16], Cv[16];
    *(float4*)&Bv[0]  = *(const float4*)(BC + row * 32);
    *(float4*)&Bv[4]  = *(const float4*)(BC + row * 32 + 4);
    *(float4*)&Bv[8]  = *(const float4*)(BC + row * 32 + 8);
    *(float4*)&Bv[12] = *(const float4*)(BC + row * 32 + 12);
    *(float4*)&Cv[0]  = *(const float4*)(BC + row * 32 + 16);
    *(float4*)&Cv[4]  = *(const float4*)(BC + row * 32 + 20);
    *(float4*)&Cv[8]  = *(const float4*)(BC + row * 32 + 24);
    *(float4*)&Cv[12] = *(const float4*)(BC + row * 32 + 28);
    for (int i = 0; i < SC_LEN; ++i) {
      float ndt = 0.f, nu = 0.f, nz = 0.f;
      float NBv[16], NCv[16];
      if (i + 1 < SC_LEN) {
        const size_t nrow = row + 1;
        ndt = dt[nrow * DIN_ + d];
        nu = bf2f(u[nrow * DIN_ + d]);
        nz = bf2f(xz[nrow * (2 * DIN_) + DIN_ + d]);
        *(float4*)&NBv[0]  = *(const float4*)(BC + nrow * 32);
        *(float4*)&NBv[4]  = *(const float4*)(BC + nrow * 32 + 4);
        *(float4*)&NBv[8]  = *(const float4*)(BC + nrow * 32 + 8);
        *(float4*)&NBv[12] = *(const float4*)(BC + nrow * 32 + 12);
        *(float4*)&NCv[0]  = *(const float4*)(BC + nrow * 32 + 16);
        *(float4*)&NCv[4]  = *(const float4*)(BC + nrow * 32 + 20);
        *(float4*)&NCv[8]  = *(const float4*)(BC + nrow * 32 + 24);
        *(float4*)&NCv[12] = *(const float4*)(BC + nrow * 32 + 28);
      }
      const float du = dtv * uv;
      float y = uv * Dpd;
      float dA[16];
      dAcalc<FAST>(dtv, A0, A, dA);
#pragma unroll
      for (int n = 0; n < 16; ++n) {
        h[n] = fmaf(dA[n], h[n], du * Bv[n]);
        y = fmaf(h[n], Cv[n], y);
      }
      y *= zv / (1.f + __expf(-zv));
      u[row * DIN_ + d] = f2bf(y);
      dtv = ndt; uv = nu; zv = nz;
#pragma unroll
      for (int n = 0; n < 16; ++n) { Bv[n] = NBv[n]; Cv[n] = NCv[n]; }
      row += 1;
    }
  }
}

// Block = (b, 16-channel group). 512 thr = 16 channels x 32 chunks (32 steps).
__global__ __launch_bounds__(512) void scan5_k(
    const float* __restrict__ dt, ushort* u,
    const float* __restrict__ BC, const ushort* __restrict__ xz,
    const float* __restrict__ A_log, const float* __restrict__ Dp)
{
  const int tid = threadIdx.x;
  const int g = tid & (SC_G - 1);
  const int c = tid >> 4;
  const int b = blockIdx.x >> 6;                 // DIN_/SC_G = 64 groups
  const int d0 = (blockIdx.x & 63) * SC_G;
  const int d = d0 + g;

  __shared__ float Hs[SC_C][SC_G][NST_ + 1];
  __shared__ float Ss[SC_C][SC_G];
  __shared__ int slow;
  if (tid == 0) slow = 0;
  __syncthreads();

  float A[16];
#pragma unroll
  for (int n = 0; n < 16; ++n) A[n] = -expf(A_log[d * NST_ + n]);
  const float A0 = A[0];
  bool myfast = true;
#pragma unroll
  for (int n = 1; n < 16; ++n)
    myfast = myfast && (fabsf(A[n] - (float)(n + 1) * A0) <= 1e-3f * fabsf(A[n]));
  if (!myfast) slow = 1;
  __syncthreads();
  const float Dpd = Dp[d];
  const size_t base = (size_t)b * L_;

  if (slow == 0)
    scan_run<true>(dt, u, BC, xz, A_log, A, A0, Dpd, Hs, Ss, tid, g, c, d0, d, base);
  else
    scan_run<false>(dt, u, BC, xz, A_log, A, A0, Dpd, Hs, Ss, tid, g, c, d0, d, base);
}

// ---------------------------------------------------------------------------
// Small helper kernels
// ---------------------------------------------------------------------------
__global__ __launch_bounds__(256) void cvt_k(const float* __restrict__ in,
                                             ushort* __restrict__ out, int n8)
{
  const int i = blockIdx.x * 256 + threadIdx.x;
  if (i >= n8) return;
  const float4 a = *(const float4*)(in + (size_t)i * 8);
  const float4 b = *(const float4*)(in + (size_t)i * 8 + 4);
  short8 s;
  s[0] = (short)f2bf(a.x); s[1] = (short)f2bf(a.y);
  s[2] = (short)f2bf(a.z); s[3] = (short)f2bf(a.w);
  s[4] = (short)f2bf(b.x); s[5] = (short)f2bf(b.y);
  s[6] = (short)f2bf(b.z); s[7] = (short)f2bf(b.w);
  *(short8*)(out + (size_t)i * 8) = s;
}

// tconv_w (O,I,3) -> bf16 (O, tap*512 + d)
__global__ __launch_bounds__(256) void twt_k(const float* __restrict__ in,
                                             ushort* __restrict__ out)
{
  const int i = blockIdx.x * 256 + threadIdx.x;
  if (i >= D_ * D_ * 3) return;
  const int o = i / (D_ * 3);
  const int rem = i - o * (D_ * 3);
  const int d = rem / 3;
  const int tap = rem - d * 3;
  out[(size_t)o * (D_ * 3) + tap * D_ + d] = f2bf(in[i]);
}

// x_proj_w[0:32] (32,1024) -> bf16 transpose (1024,32)
__global__ __launch_bounds__(256) void xpT_k(const float* __restrict__ xpw,
                                             ushort* __restrict__ out)
{
  const int i = blockIdx.x * 256 + threadIdx.x;
  if (i >= DIN_ * DTR_) return;
  const int k = i >> 5;
  const int r = i & 31;
  out[i] = f2bf(xpw[(size_t)r * DIN_ + k]);
}

// Wbig (1088,1024) bf16 = [Wcomb fp32 (1024); x_proj_w[32:64] (32); zeros(32)]
__global__ __launch_bounds__(256) void pack_k(const float* __restrict__ wc,
                                              const float* __restrict__ xpw,
                                              ushort* __restrict__ wbig)
{
  const int i = blockIdx.x * 256 + threadIdx.x;
  if (i >= 1088 * 1024) return;
  const int r = i >> 10;
  const int k = i & 1023;
  float v;
  if (r < 1024) v = wc[i];
  else if (r < 1056) v = xpw[(size_t)(DTR_ + r - 1024) * DIN_ + k];
  else v = 0.f;
  wbig[i] = f2bf(v);
}

// ---------------------------------------------------------------------------
extern "C" void kernel_launch(void* const* d_in, const int* in_sizes, int n_in,
                              void* d_out, int out_size, void* d_ws, size_t ws_size,
                              hipStream_t stream)
{
  const float* x         = (const float*)d_in[0];
  const float* tconv_w   = (const float*)d_in[1];
  const float* tconv_b   = (const float*)d_in[2];
  const float* tnorm_w   = (const float*)d_in[3];
  const float* tnorm_b   = (const float*)d_in[4];
  const float* ln1_w     = (const float*)d_in[5];
  const float* ln1_b     = (const float*)d_in[6];
  const float* in_proj_w = (const float*)d_in[7];
  const float* conv_w    = (const float*)d_in[8];
  const float* conv_b    = (const float*)d_in[9];
  const float* x_proj_w  = (const float*)d_in[10];
  const float* dt_proj_w = (const float*)d_in[11];
  const float* dt_proj_b = (const float*)d_in[12];
  const float* A_log     = (const float*)d_in[13];
  const float* D_param   = (const float*)d_in[14];
  const float* out_proj_w= (const float*)d_in[15];
  const float* ln2_w     = (const float*)d_in[16];
  const float* ln2_b     = (const float*)d_in[17];
  const float* ffn_w1    = (const float*)d_in[18];
  const float* ffn_b1    = (const float*)d_in[19];
  const float* ffn_w2    = (const float*)d_in[20];
  const float* ffn_b2    = (const float*)d_in[21];

  float* h = (float*)d_out;

  // ---- workspace layout ----
  char* p = (char*)d_ws;
  ushort* wTT  = (ushort*)p; p += (size_t)512 * 1536 * 2;
  ushort* wIP  = (ushort*)p; p += (size_t)4 * 2048 * 512 * 2;
  ushort* wOP  = (ushort*)p; p += (size_t)4 * 512 * 1024 * 2;
  ushort* wF1  = (ushort*)p; p += (size_t)4 * 1024 * 512 * 2;
  ushort* wF2  = (ushort*)p; p += (size_t)4 * 512 * 1024 * 2;
  ushort* xpwT = (ushort*)p; p += (size_t)4 * 1024 * 32 * 2;
  ushort* wBig = (ushort*)p; p += (size_t)4 * 1088 * 1024 * 2;
  float*  wcT  = (float*)p;  p += (size_t)1024 * 1024 * 4;
  ushort* xin  = (ushort*)p; p += (size_t)M_ * 512 * 2;
  ushort* xzb  = (ushort*)p; p += (size_t)M_ * 2048 * 2;
  ushort* ubuf = (ushort*)p; p += (size_t)M_ * 1024 * 2;
  float*  bc   = (float*)p;  p += (size_t)M_ * 32 * 4;
  float*  dtb  = (float*)p;  p += (size_t)M_ * 1024 * 4;
  ushort* ff   = (ushort*)p; p += (size_t)M_ * 1024 * 2;

  const dim3 blk(256);

  // ---- preprocessing: weights -> bf16, Wcomb = dt_proj_w @ x_proj_w[0:32] ----
  cvt_k<<<dim3(4 * 2048 * 512 / 8 / 256), blk, 0, stream>>>(in_proj_w, wIP, 4 * 2048 * 512 / 8);
  cvt_k<<<dim3(4 * 512 * 1024 / 8 / 256), blk, 0, stream>>>(out_proj_w, wOP, 4 * 512 * 1024 / 8);
  cvt_k<<<dim3(4 * 1024 * 512 / 8 / 256), blk, 0, stream>>>(ffn_w1, wF1, 4 * 1024 * 512 / 8);
  cvt_k<<<dim3(4 * 512 * 1024 / 8 / 256), blk, 0, stream>>>(ffn_w2, wF2, 4 * 512 * 1024 / 8);
  twt_k<<<dim3((D_ * D_ * 3 + 255) / 256), blk, 0, stream>>>(tconv_w, wTT);
  for (int i = 0; i < NB_; ++i)
    xpT_k<<<dim3(DIN_ * DTR_ / 256), blk, 0, stream>>>(
        x_proj_w + (size_t)i * 64 * DIN_, xpwT + (size_t)i * DIN_ * DTR_);
  for (int i = 0; i < NB_; ++i) {
    mgemm_k<0, 0, 128, 1, 0><<<dim3(8, 8), blk, 0, stream>>>(
        dt_proj_w + (size_t)i * DIN_ * DTR_, xpwT + (size_t)i * DIN_ * DTR_,
        nullptr, wcT, nullptr, 1024, 1024, 32, 32, 1024);
    pack_k<<<dim3(1088 * 1024 / 256), blk, 0, stream>>>(
        wcT, x_proj_w + (size_t)i * 64 * DIN_, wBig + (size_t)i * 1088 * 1024);
  }

  // ---- temporal conv (GEMM + fused im2col) + LN(hc + x) -> h ----
  mgemm_k<1, 1, 64, 1, 1><<<dim3(8, 64), blk, 0, stream>>>(
      x, wTT, tconv_b, xin, nullptr, M_, 512, 1536, 0, 512);
  ln_k<1, 0><<<dim3(M_), blk, 0, stream>>>(xin, x, tnorm_w, tnorm_b, h);

  for (int i = 0; i < NB_; ++i) {
    // xin = LN(h)  (bf16)
    ln_k<0, 1><<<dim3(M_), blk, 0, stream>>>(h, nullptr, ln1_w + i * D_, ln1_b + i * D_, xin);
    // xz = xin @ in_proj^T  (bf16)
    mgemm_k<0, 0, 128, 0, 1><<<dim3(16, 64), blk, 0, stream>>>(
        xin, wIP + (size_t)i * 2048 * 512, nullptr, xzb, nullptr,
        M_, 2048, 512, 512, 2048);
    // u = silu(dwconv(xz_u) + cb)  (bf16)
    dwconv_k<<<dim3(M_ * DIN_ / 8 / 256), blk, 0, stream>>>(
        xzb, conv_w + (size_t)i * DIN_ * 4, conv_b + (size_t)i * DIN_, ubuf);
    // dt (softplus, fp32) + B/C (fp32) in one GEMM vs Wbig
    mgemm_k<0, 6, 64, 0, 0><<<dim3(17, 64), blk, 0, stream>>>(
        ubuf, wBig + (size_t)i * 1088 * 1024, dt_proj_b + (size_t)i * DIN_,
        dtb, bc, M_, 1088, 1024, 1024, 1024);
    // selective scan; ys overwrites u in place (bf16)
    scan5_k<<<dim3(B_ * (DIN_ / SC_G)), dim3(512), 0, stream>>>(
        dtb, ubuf, bc, xzb, A_log + (size_t)i * DIN_ * NST_, D_param + (size_t)i * DIN_);
    // h += ys @ out_proj^T
    mgemm_k<0, 4, 64, 0, 0><<<dim3(8, 64), blk, 0, stream>>>(
        ubuf, wOP + (size_t)i * 512 * 1024, nullptr, h, nullptr,
        M_, 512, 1024, 1024, 512);
    // hn = LN(h) (bf16); ff = gelu(hn @ w1^T + b1) (bf16); h += ff @ w2^T + b2
    ln_k<0, 1><<<dim3(M_), blk, 0, stream>>>(h, nullptr, ln2_w + i * D_, ln2_b + i * D_, xin);
    mgemm_k<0, 2, 64, 0, 1><<<dim3(16, 64), blk, 0, stream>>>(
        xin, wF1 + (size_t)i * 1024 * 512, ffn_b1 + (size_t)i * FF_, ff, nullptr,
        M_, 1024, 512, 512, 1024);
    mgemm_k<0, 5, 64, 0, 0><<<dim3(8, 64), blk, 0, stream>>>(
        ff, wF2 + (size_t)i * 512 * 1024, ffn_b2 + (size_t)i * D_, h, nullptr,
        M_, 512, 1024, 1024, 512);
  }
}

// Round 7
// 1390.477 us; speedup vs baseline: 4.6134x; 1.0598x over previous
//
#include <hip/hip_runtime.h>
#include <hip/hip_bf16.h>
#include <math.h>

#define B_ 8
#define L_ 1024
#define D_ 512
#define NB_ 4
#define DIN_ 1024
#define NST_ 16
#define DTR_ 32
#define FF_ 1024
#define EPS_LN 1e-5f
#define M_ (B_ * L_)

#define SC_G 16                 // channels per scan block
#define SC_C 32                 // L-chunks per scan block
#define SC_LEN (L_ / SC_C)      // 32 steps per chunk

typedef __attribute__((ext_vector_type(8))) short short8;
typedef __attribute__((ext_vector_type(4))) float f32x4;

static __device__ __forceinline__ ushort f2bf(float f) {
  union { float f; unsigned u; } v; v.f = f;
  unsigned r = v.u + 0x7FFFu + ((v.u >> 16) & 1u);
  return (ushort)(r >> 16);
}
static __device__ __forceinline__ float bf2f(ushort u) {
  union { unsigned u; float f; } v; v.u = ((unsigned)u) << 16;
  return v.f;
}

// async global->LDS, 16B per lane; LDS dest is wave-uniform base + lane*16
static __device__ __forceinline__ void gll16(const void* g, void* l) {
  __builtin_amdgcn_global_load_lds(
      (const __attribute__((address_space(1))) void*)g,
      (__attribute__((address_space(3))) void*)l, 16, 0, 0);
}

// ---------------------------------------------------------------------------
// Fast bf16 MFMA GEMM (A,W both bf16):  C = epi(A @ W^T (+bias))
// BK=64, BN=128, 256 threads = 4 waves (2x2), global_load_lds staging with
// source-side XOR swizzle (slot j ^= row&7 -> ds_read_b128 is 2-way, free).
// BM in {64,128}. EPI: 0 store, 2 +bias+gelu, 4 C+=, 5 C+=+bias,
//   6 dual-out: n<1024 softplus(+bias)->C fp32; 1024..1055 -> C2; else skip.
// OUTB: bf16 store (EPI 0/2).
// ---------------------------------------------------------------------------
template <int BM, int EPI, int OUTB>
__global__ __launch_bounds__(256) void mgemm2_k(
    const ushort* __restrict__ A, const ushort* __restrict__ W,
    const float* __restrict__ bias, void* __restrict__ Cp,
    float* __restrict__ C2, int M, int N, int K, int lda, int ldc)
{
  constexpr int MI = BM / 32;
  __shared__ ushort As[BM * 64];
  __shared__ ushort Bs[128 * 64];
  const int tid = threadIdx.x;
  const int lane = tid & 63;
  const int wid = tid >> 6;
  const int wm = (wid >> 1) * (BM / 2);
  const int wn = (wid & 1) * 64;
  const int bm = blockIdx.y * BM;
  const int bn = blockIdx.x * 128;
  const int fr = lane & 15;
  const int kq = lane >> 4;

  f32x4 acc[MI][4];
#pragma unroll
  for (int i = 0; i < MI; ++i)
#pragma unroll
    for (int j = 0; j < 4; ++j) acc[i][j] = (f32x4)0.f;

  for (int k0 = 0; k0 < K; k0 += 64) {
    // ---- stage A (BM x 64 bf16 = BM*128B): BM/32 wave-issues ----
#pragma unroll
    for (int it = 0; it < BM / 32; ++it) {
      const int sb = it * 4096 + wid * 1024 + lane * 16;  // byte in tile
      const int row = sb >> 7;
      const int js = (sb >> 4) & 7;
      const int j2 = js ^ (row & 7);                      // pre-swizzled src
      gll16(A + (size_t)(bm + row) * lda + k0 + j2 * 8,
            (char*)As + it * 4096 + wid * 1024);
    }
    // ---- stage B (128 x 64 bf16 = 16KB): 4 wave-issues ----
#pragma unroll
    for (int it = 0; it < 4; ++it) {
      const int sb = it * 4096 + wid * 1024 + lane * 16;
      const int row = sb >> 7;
      const int js = (sb >> 4) & 7;
      const int j2 = js ^ (row & 7);
      gll16(W + (size_t)(bn + row) * K + k0 + j2 * 8,
            (char*)Bs + it * 4096 + wid * 1024);
    }
    __syncthreads();
#pragma unroll
    for (int kk = 0; kk < 2; ++kk) {
      short8 af[MI], bf[4];
#pragma unroll
      for (int mi = 0; mi < MI; ++mi) {
        const int r = wm + mi * 16 + fr;
        af[mi] = *(const short8*)&As[r * 64 + ((((kk << 2) + kq) ^ (r & 7)) << 3)];
      }
#pragma unroll
      for (int ni = 0; ni < 4; ++ni) {
        const int r = wn + ni * 16 + fr;
        bf[ni] = *(const short8*)&Bs[r * 64 + ((((kk << 2) + kq) ^ (r & 7)) << 3)];
      }
#pragma unroll
      for (int mi = 0; mi < MI; ++mi)
#pragma unroll
        for (int ni = 0; ni < 4; ++ni)
          acc[mi][ni] = __builtin_amdgcn_mfma_f32_16x16x32_bf16(
              af[mi], bf[ni], acc[mi][ni], 0, 0, 0);
    }
    __syncthreads();
  }

  // ---- epilogue: D layout col=lane&15, row=(lane>>4)*4+reg ----
#pragma unroll
  for (int mi = 0; mi < MI; ++mi) {
#pragma unroll
    for (int ni = 0; ni < 4; ++ni) {
#pragma unroll
      for (int r = 0; r < 4; ++r) {
        const int gm = bm + wm + mi * 16 + (lane >> 4) * 4 + r;
        const int gn = bn + wn + ni * 16 + fr;
        float v = acc[mi][ni][r];
        if (EPI == 6) {
          if (gn < DIN_) {
            v += bias[gn];
            v = (v > 20.f) ? v : __logf(1.f + __expf(v));
            ((float*)Cp)[(size_t)gm * DIN_ + gn] = v;
          } else if (gn < DIN_ + 2 * NST_) {
            C2[(size_t)gm * (2 * NST_) + (gn - DIN_)] = v;
          }
        } else {
          if (EPI == 2 || EPI == 5) v += bias[gn];
          if (EPI == 2) v = 0.5f * v * (1.f + erff(v * 0.70710678118654752f));
          if (OUTB) {
            ((ushort*)Cp)[(size_t)gm * ldc + gn] = f2bf(v);
          } else {
            float* pc = (float*)Cp + (size_t)gm * ldc + gn;
            if (EPI == 4 || EPI == 5) v += *pc;
            *pc = v;
          }
        }
      }
    }
  }
}

// ---------------------------------------------------------------------------
// Legacy GEMM (fp32-A paths: tconv im2col + Wcomb), BK=32, reg staging.
// MODE 0: A[m*lda+k] fp32.  MODE 1: im2col of fp32 x (B,L,D).
// EPI: 0 store, 1 +bias. OUTB: bf16 out.
// ---------------------------------------------------------------------------
template <int MODE, int EPI, int BN, int OUTB>
__global__ __launch_bounds__(256) void mgemm_k(
    const float* __restrict__ Ap, const ushort* __restrict__ W,
    const float* __restrict__ bias, void* __restrict__ Cp,
    int M, int N, int K, int lda, int ldc)
{
  constexpr int FN = BN / 32;
  __shared__ ushort As[128 * 32];
  __shared__ ushort Bs[BN * 32];
  const int tid = threadIdx.x;
  const int lane = tid & 63;
  const int wid = tid >> 6;
  const int wm = (wid >> 1) * 64;
  const int wn = (wid & 1) * (BN / 2);
  const int bm = blockIdx.y * 128;
  const int bn = blockIdx.x * BN;
  const int fr = lane & 15;
  const int kq = lane >> 4;

  f32x4 acc[4][FN];
#pragma unroll
  for (int i = 0; i < 4; ++i)
#pragma unroll
    for (int j = 0; j < FN; ++j) acc[i][j] = (f32x4)0.f;

  for (int k0 = 0; k0 < K; k0 += 32) {
#pragma unroll
    for (int it = 0; it < 2; ++it) {
      const int idx = tid + it * 256;
      const int row = idx >> 2;
      const int j = idx & 3;
      short8 s;
      float4 v0, v1;
      if (MODE == 0) {
        const float* p = Ap + (size_t)(bm + row) * lda + k0 + j * 8;
        v0 = *(const float4*)p; v1 = *(const float4*)(p + 4);
      } else {
        const int kk = k0 + j * 8;
        const int tap = kk >> 9;
        const int dcol = kk & 511;
        const int m = bm + row;
        const int l = (m & (L_ - 1)) + tap - 1;
        if (l >= 0 && l < L_) {
          const float* p = Ap + (size_t)(m - (m & (L_ - 1)) + l) * D_ + dcol;
          v0 = *(const float4*)p; v1 = *(const float4*)(p + 4);
        } else {
          v0 = make_float4(0.f, 0.f, 0.f, 0.f); v1 = v0;
        }
      }
      s[0] = (short)f2bf(v0.x); s[1] = (short)f2bf(v0.y);
      s[2] = (short)f2bf(v0.z); s[3] = (short)f2bf(v0.w);
      s[4] = (short)f2bf(v1.x); s[5] = (short)f2bf(v1.y);
      s[6] = (short)f2bf(v1.z); s[7] = (short)f2bf(v1.w);
      *(short8*)&As[row * 32 + ((j ^ ((row >> 1) & 3)) << 3)] = s;
    }
#pragma unroll
    for (int it = 0; it < BN / 64; ++it) {
      const int idx = tid + it * 256;
      const int row = idx >> 2;
      const int j = idx & 3;
      short8 s = *(const short8*)(W + (size_t)(bn + row) * K + k0 + j * 8);
      *(short8*)&Bs[row * 32 + ((j ^ ((row >> 1) & 3)) << 3)] = s;
    }
    __syncthreads();
    short8 af[4], bfr[FN];
#pragma unroll
    for (int mi = 0; mi < 4; ++mi) {
      const int r = wm + mi * 16 + fr;
      af[mi] = *(const short8*)&As[r * 32 + ((kq ^ ((r >> 1) & 3)) << 3)];
    }
#pragma unroll
    for (int ni = 0; ni < FN; ++ni) {
      const int r = wn + ni * 16 + fr;
      bfr[ni] = *(const short8*)&Bs[r * 32 + ((kq ^ ((r >> 1) & 3)) << 3)];
    }
#pragma unroll
    for (int mi = 0; mi < 4; ++mi)
#pragma unroll
      for (int ni = 0; ni < FN; ++ni)
        acc[mi][ni] = __builtin_amdgcn_mfma_f32_16x16x32_bf16(
            af[mi], bfr[ni], acc[mi][ni], 0, 0, 0);
    __syncthreads();
  }

#pragma unroll
  for (int mi = 0; mi < 4; ++mi) {
#pragma unroll
    for (int ni = 0; ni < FN; ++ni) {
#pragma unroll
      for (int r = 0; r < 4; ++r) {
        const int gm = bm + wm + mi * 16 + (lane >> 4) * 4 + r;
        const int gn = bn + wn + ni * 16 + fr;
        float v = acc[mi][ni][r];
        if (EPI == 1) v += bias[gn];
        if (OUTB) ((ushort*)Cp)[(size_t)gm * ldc + gn] = f2bf(v);
        else ((float*)Cp)[(size_t)gm * ldc + gn] = v;
      }
    }
  }
}

// ---------------------------------------------------------------------------
// LayerNorm over last dim 512. INB: input bf16. OUTB: output bf16.
// ---------------------------------------------------------------------------
template <int INB, int OUTB>
__global__ __launch_bounds__(256) void ln_k(
    const void* __restrict__ inp, const float* __restrict__ res,
    const float* __restrict__ w, const float* __restrict__ b,
    void* __restrict__ outp)
{
  const int row = blockIdx.x;
  const int t = threadIdx.x;
  float v0, v1;
  if (INB) {
    const ushort* p = (const ushort*)inp + (size_t)row * D_;
    v0 = bf2f(p[t]); v1 = bf2f(p[t + 256]);
  } else {
    const float* p = (const float*)inp + (size_t)row * D_;
    v0 = p[t]; v1 = p[t + 256];
  }
  if (res) {
    const float* r = res + (size_t)row * D_;
    v0 += r[t]; v1 += r[t + 256];
  }
  float s = v0 + v1;
  float sq = v0 * v0 + v1 * v1;
#pragma unroll
  for (int m = 1; m < 64; m <<= 1) {
    s += __shfl_xor(s, m, 64);
    sq += __shfl_xor(sq, m, 64);
  }
  __shared__ float ss[4], qq[4];
  const int wid = t >> 6;
  if ((t & 63) == 0) { ss[wid] = s; qq[wid] = sq; }
  __syncthreads();
  s = ss[0] + ss[1] + ss[2] + ss[3];
  sq = qq[0] + qq[1] + qq[2] + qq[3];
  const float mu = s * (1.f / (float)D_);
  const float var = sq * (1.f / (float)D_) - mu * mu;
  const float rs = rsqrtf(var + EPS_LN);
  const float o0 = (v0 - mu) * rs * w[t] + b[t];
  const float o1 = (v1 - mu) * rs * w[t + 256] + b[t + 256];
  if (OUTB) {
    ushort* o = (ushort*)outp + (size_t)row * D_;
    o[t] = f2bf(o0); o[t + 256] = f2bf(o1);
  } else {
    float* o = (float*)outp + (size_t)row * D_;
    o[t] = o0; o[t + 256] = o1;
  }
}

// ---------------------------------------------------------------------------
// Depthwise causal conv (k=4, pad 3), vectorized 8 channels/thread.
// ---------------------------------------------------------------------------
__global__ __launch_bounds__(256) void dwconv_k(
    const ushort* __restrict__ xz, const float* __restrict__ cw,
    const float* __restrict__ cb, ushort* __restrict__ u)
{
  const int idx = blockIdx.x * 256 + threadIdx.x;   // M_*DIN_/8 threads
  const int c8 = idx & (DIN_ / 8 - 1);
  const int bl = idx >> 7;
  const int l = bl & (L_ - 1);
  const int b0 = bl - l;
  const int c0 = c8 * 8;
  float s[8], w[8][4];
#pragma unroll
  for (int j = 0; j < 8; ++j) {
    s[j] = cb[c0 + j];
    const float4 wv = *(const float4*)(cw + (c0 + j) * 4);
    w[j][0] = wv.x; w[j][1] = wv.y; w[j][2] = wv.z; w[j][3] = wv.w;
  }
#pragma unroll
  for (int k = 0; k < 4; ++k) {
    const int ll = l + k - 3;
    if (ll >= 0) {
      const short8 v = *(const short8*)(xz + (size_t)(b0 + ll) * (2 * DIN_) + c0);
#pragma unroll
      for (int j = 0; j < 8; ++j)
        s[j] = fmaf(bf2f((ushort)v[j]), w[j][k], s[j]);
    }
  }
  short8 o;
#pragma unroll
  for (int j = 0; j < 8; ++j) {
    const float t = s[j] / (1.f + __expf(-s[j]));
    o[j] = (short)f2bf(t);
  }
  *(short8*)(u + (size_t)idx * 8) = o;
}

// ---------------------------------------------------------------------------
// Selective scan helpers: dA[n] = exp(dt*A[n]).
// FAST path exploits A[n] = (n+1)*A[0]: one exp + 15 muls. Runtime-verified.
// ---------------------------------------------------------------------------
template <bool FAST>
static __device__ __forceinline__ void dAcalc(float dtv, float A0,
                                              const float* A, float* dA)
{
  if (FAST) {
    const float e = __expf(dtv * A0);
    dA[0] = e;
#pragma unroll
    for (int n = 1; n < 16; ++n) dA[n] = dA[n - 1] * e;
  } else {
#pragma unroll
    for (int n = 0; n < 16; ++n) dA[n] = __expf(dtv * A[n]);
  }
}

template <bool FAST>
static __device__ __forceinline__ void scan_run(
    const float* __restrict__ dt, ushort* __restrict__ u,
    const float* __restrict__ BC, const ushort* __restrict__ xz,
    const float* __restrict__ A_log,
    const float* A, const float A0, const float Dpd,
    float (*Hs)[SC_G][NST_ + 1], float (*Ss)[SC_G],
    const int tid, const int g, const int c, const int d0, const int d,
    const size_t base)
{
  const int l0 = c * SC_LEN;
  float h[16];
#pragma unroll
  for (int n = 0; n < 16; ++n) h[n] = 0.f;
  float S = 0.f;

  // ---------------- pass 1 ----------------
  {
    size_t row = base + l0;
    float dtv = dt[row * DIN_ + d];
    float uv = bf2f(u[row * DIN_ + d]);
    float Bv[16];
    *(float4*)&Bv[0]  = *(const float4*)(BC + row * 32);
    *(float4*)&Bv[4]  = *(const float4*)(BC + row * 32 + 4);
    *(float4*)&Bv[8]  = *(const float4*)(BC + row * 32 + 8);
    *(float4*)&Bv[12] = *(const float4*)(BC + row * 32 + 12);
    for (int i = 0; i < SC_LEN; ++i) {
      float ndt = 0.f, nu = 0.f;
      float NBv[16];
      if (i + 1 < SC_LEN) {
        const size_t nrow = row + 1;
        ndt = dt[nrow * DIN_ + d];
        nu = bf2f(u[nrow * DIN_ + d]);
        *(float4*)&NBv[0]  = *(const float4*)(BC + nrow * 32);
        *(float4*)&NBv[4]  = *(const float4*)(BC + nrow * 32 + 4);
        *(float4*)&NBv[8]  = *(const float4*)(BC + nrow * 32 + 8);
        *(float4*)&NBv[12] = *(const float4*)(BC + nrow * 32 + 12);
      }
      S += dtv;
      const float du = dtv * uv;
      float dA[16];
      dAcalc<FAST>(dtv, A0, A, dA);
#pragma unroll
      for (int n = 0; n < 16; ++n)
        h[n] = fmaf(dA[n], h[n], du * Bv[n]);
      dtv = ndt; uv = nu;
#pragma unroll
      for (int n = 0; n < 16; ++n) Bv[n] = NBv[n];
      row += 1;
    }
  }
#pragma unroll
  for (int n = 0; n < 16; ++n) Hs[c][g][n] = h[n];
  Ss[c][g] = S;
  __syncthreads();

  // ---------------- serial chunk combine ----------------
  if (tid < SC_G * NST_) {
    const int gg = tid >> 4;
    const int n2 = tid & 15;
    const float An = -expf(A_log[(d0 + gg) * NST_ + n2]);
    float hin = 0.f;
#pragma unroll
    for (int cc = 0; cc < SC_C; ++cc) {
      const float tmp = Hs[cc][gg][n2];
      const float P = __expf(An * Ss[cc][gg]);
      Hs[cc][gg][n2] = hin;
      hin = tmp + P * hin;
    }
  }
  __syncthreads();

  // ---------------- pass 2 ----------------
#pragma unroll
  for (int n = 0; n < 16; ++n) h[n] = Hs[c][g][n];
  {
    size_t row = base + l0;
    float dtv = dt[row * DIN_ + d];
    float uv = bf2f(u[row * DIN_ + d]);
    float zv = bf2f(xz[row * (2 * DIN_) + DIN_ + d]);
    float Bv[16], Cv[16];
    *(float4*)&Bv[0]  = *(const float4*)(BC + row * 32);
    *(float4*)&Bv[4]  = *(const float4*)(BC + row * 32 + 4);
    *(float4*)&Bv[8]  = *(const float4*)(BC + row * 32 + 8);
    *(float4*)&Bv[12] = *(const float4*)(BC + row * 32 + 12);
    *(float4*)&Cv[0]  = *(const float4*)(BC + row * 32 + 16);
    *(float4*)&Cv[4]  = *(const float4*)(BC + row * 32 + 20);
    *(float4*)&Cv[8]  = *(const float4*)(BC + row * 32 + 24);
    *(float4*)&Cv[12] = *(const float4*)(BC + row * 32 + 28);
    for (int i = 0; i < SC_LEN; ++i) {
      float ndt = 0.f, nu = 0.f, nz = 0.f;
      float NBv[16], NCv[16];
      if (i + 1 < SC_LEN) {
        const size_t nrow = row + 1;
        ndt = dt[nrow * DIN_ + d];
        nu = bf2f(u[nrow * DIN_ + d]);
        nz = bf2f(xz[nrow * (2 * DIN_) + DIN_ + d]);
        *(float4*)&NBv[0]  = *(const float4*)(BC + nrow * 32);
        *(float4*)&NBv[4]  = *(const float4*)(BC + nrow * 32 + 4);
        *(float4*)&NBv[8]  = *(const float4*)(BC + nrow * 32 + 8);
        *(float4*)&NBv[12] = *(const float4*)(BC + nrow * 32 + 12);
        *(float4*)&NCv[0]  = *(const float4*)(BC + nrow * 32 + 16);
        *(float4*)&NCv[4]  = *(const float4*)(BC + nrow * 32 + 20);
        *(float4*)&NCv[8]  = *(const float4*)(BC + nrow * 32 + 24);
        *(float4*)&NCv[12] = *(const float4*)(BC + nrow * 32 + 28);
      }
      const float du = dtv * uv;
      float y = uv * Dpd;
      float dA[16];
      dAcalc<FAST>(dtv, A0, A, dA);
#pragma unroll
      for (int n = 0; n < 16; ++n) {
        h[n] = fmaf(dA[n], h[n], du * Bv[n]);
        y = fmaf(h[n], Cv[n], y);
      }
      y *= zv / (1.f + __expf(-zv));
      u[row * DIN_ + d] = f2bf(y);
      dtv = ndt; uv = nu; zv = nz;
#pragma unroll
      for (int n = 0; n < 16; ++n) { Bv[n] = NBv[n]; Cv[n] = NCv[n]; }
      row += 1;
    }
  }
}

// Block = (b, 16-channel group). 512 thr = 16 channels x 32 chunks (32 steps).
__global__ __launch_bounds__(512) void scan5_k(
    const float* __restrict__ dt, ushort* u,
    const float* __restrict__ BC, const ushort* __restrict__ xz,
    const float* __restrict__ A_log, const float* __restrict__ Dp)
{
  const int tid = threadIdx.x;
  const int g = tid & (SC_G - 1);
  const int c = tid >> 4;
  const int b = blockIdx.x >> 6;
  const int d0 = (blockIdx.x & 63) * SC_G;
  const int d = d0 + g;

  __shared__ float Hs[SC_C][SC_G][NST_ + 1];
  __shared__ float Ss[SC_C][SC_G];
  __shared__ int slow;
  if (tid == 0) slow = 0;
  __syncthreads();

  float A[16];
#pragma unroll
  for (int n = 0; n < 16; ++n) A[n] = -expf(A_log[d * NST_ + n]);
  const float A0 = A[0];
  bool myfast = true;
#pragma unroll
  for (int n = 1; n < 16; ++n)
    myfast = myfast && (fabsf(A[n] - (float)(n + 1) * A0) <= 1e-3f * fabsf(A[n]));
  if (!myfast) slow = 1;
  __syncthreads();
  const float Dpd = Dp[d];
  const size_t base = (size_t)b * L_;

  if (slow == 0)
    scan_run<true>(dt, u, BC, xz, A_log, A, A0, Dpd, Hs, Ss, tid, g, c, d0, d, base);
  else
    scan_run<false>(dt, u, BC, xz, A_log, A, A0, Dpd, Hs, Ss, tid, g, c, d0, d, base);
}

// ---------------------------------------------------------------------------
// Small helper kernels
// ---------------------------------------------------------------------------
__global__ __launch_bounds__(256) void cvt_k(const float* __restrict__ in,
                                             ushort* __restrict__ out, int n8)
{
  const int i = blockIdx.x * 256 + threadIdx.x;
  if (i >= n8) return;
  const float4 a = *(const float4*)(in + (size_t)i * 8);
  const float4 b = *(const float4*)(in + (size_t)i * 8 + 4);
  short8 s;
  s[0] = (short)f2bf(a.x); s[1] = (short)f2bf(a.y);
  s[2] = (short)f2bf(a.z); s[3] = (short)f2bf(a.w);
  s[4] = (short)f2bf(b.x); s[5] = (short)f2bf(b.y);
  s[6] = (short)f2bf(b.z); s[7] = (short)f2bf(b.w);
  *(short8*)(out + (size_t)i * 8) = s;
}

// tconv_w (O,I,3) -> bf16 (O, tap*512 + d)
__global__ __launch_bounds__(256) void twt_k(const float* __restrict__ in,
                                             ushort* __restrict__ out)
{
  const int i = blockIdx.x * 256 + threadIdx.x;
  if (i >= D_ * D_ * 3) return;
  const int o = i / (D_ * 3);
  const int rem = i - o * (D_ * 3);
  const int d = rem / 3;
  const int tap = rem - d * 3;
  out[(size_t)o * (D_ * 3) + tap * D_ + d] = f2bf(in[i]);
}

// x_proj_w[0:32] (32,1024) -> bf16 transpose (1024,32)
__global__ __launch_bounds__(256) void xpT_k(const float* __restrict__ xpw,
                                             ushort* __restrict__ out)
{
  const int i = blockIdx.x * 256 + threadIdx.x;
  if (i >= DIN_ * DTR_) return;
  const int k = i >> 5;
  const int r = i & 31;
  out[i] = f2bf(xpw[(size_t)r * DIN_ + k]);
}

// Wbig (1152,1024) bf16 = [Wcomb (1024); x_proj_w[32:64] (32); zeros(96)]
__global__ __launch_bounds__(256) void pack_k(const float* __restrict__ wc,
                                              const float* __restrict__ xpw,
                                              ushort* __restrict__ wbig)
{
  const int i = blockIdx.x * 256 + threadIdx.x;
  if (i >= 1152 * 1024) return;
  const int r = i >> 10;
  const int k = i & 1023;
  float v;
  if (r < 1024) v = wc[i];
  else if (r < 1056) v = xpw[(size_t)(DTR_ + r - 1024) * DIN_ + k];
  else v = 0.f;
  wbig[i] = f2bf(v);
}

// ---------------------------------------------------------------------------
extern "C" void kernel_launch(void* const* d_in, const int* in_sizes, int n_in,
                              void* d_out, int out_size, void* d_ws, size_t ws_size,
                              hipStream_t stream)
{
  const float* x         = (const float*)d_in[0];
  const float* tconv_w   = (const float*)d_in[1];
  const float* tconv_b   = (const float*)d_in[2];
  const float* tnorm_w   = (const float*)d_in[3];
  const float* tnorm_b   = (const float*)d_in[4];
  const float* ln1_w     = (const float*)d_in[5];
  const float* ln1_b     = (const float*)d_in[6];
  const float* in_proj_w = (const float*)d_in[7];
  const float* conv_w    = (const float*)d_in[8];
  const float* conv_b    = (const float*)d_in[9];
  const float* x_proj_w  = (const float*)d_in[10];
  const float* dt_proj_w = (const float*)d_in[11];
  const float* dt_proj_b = (const float*)d_in[12];
  const float* A_log     = (const float*)d_in[13];
  const float* D_param   = (const float*)d_in[14];
  const float* out_proj_w= (const float*)d_in[15];
  const float* ln2_w     = (const float*)d_in[16];
  const float* ln2_b     = (const float*)d_in[17];
  const float* ffn_w1    = (const float*)d_in[18];
  const float* ffn_b1    = (const float*)d_in[19];
  const float* ffn_w2    = (const float*)d_in[20];
  const float* ffn_b2    = (const float*)d_in[21];

  float* h = (float*)d_out;

  // ---- workspace layout ----
  char* p = (char*)d_ws;
  ushort* wTT  = (ushort*)p; p += (size_t)512 * 1536 * 2;
  ushort* wIP  = (ushort*)p; p += (size_t)4 * 2048 * 512 * 2;
  ushort* wOP  = (ushort*)p; p += (size_t)4 * 512 * 1024 * 2;
  ushort* wF1  = (ushort*)p; p += (size_t)4 * 1024 * 512 * 2;
  ushort* wF2  = (ushort*)p; p += (size_t)4 * 512 * 1024 * 2;
  ushort* xpwT = (ushort*)p; p += (size_t)4 * 1024 * 32 * 2;
  ushort* wBig = (ushort*)p; p += (size_t)4 * 1152 * 1024 * 2;
  float*  wcT  = (float*)p;  p += (size_t)1024 * 1024 * 4;
  ushort* xin  = (ushort*)p; p += (size_t)M_ * 512 * 2;
  ushort* xzb  = (ushort*)p; p += (size_t)M_ * 2048 * 2;
  ushort* ubuf = (ushort*)p; p += (size_t)M_ * 1024 * 2;
  float*  bc   = (float*)p;  p += (size_t)M_ * 32 * 4;
  float*  dtb  = (float*)p;  p += (size_t)M_ * 1024 * 4;
  ushort* ff   = (ushort*)p; p += (size_t)M_ * 1024 * 2;

  const dim3 blk(256);

  // ---- preprocessing: weights -> bf16, Wcomb = dt_proj_w @ x_proj_w[0:32] ----
  cvt_k<<<dim3(4 * 2048 * 512 / 8 / 256), blk, 0, stream>>>(in_proj_w, wIP, 4 * 2048 * 512 / 8);
  cvt_k<<<dim3(4 * 512 * 1024 / 8 / 256), blk, 0, stream>>>(out_proj_w, wOP, 4 * 512 * 1024 / 8);
  cvt_k<<<dim3(4 * 1024 * 512 / 8 / 256), blk, 0, stream>>>(ffn_w1, wF1, 4 * 1024 * 512 / 8);
  cvt_k<<<dim3(4 * 512 * 1024 / 8 / 256), blk, 0, stream>>>(ffn_w2, wF2, 4 * 512 * 1024 / 8);
  twt_k<<<dim3((D_ * D_ * 3 + 255) / 256), blk, 0, stream>>>(tconv_w, wTT);
  for (int i = 0; i < NB_; ++i)
    xpT_k<<<dim3(DIN_ * DTR_ / 256), blk, 0, stream>>>(
        x_proj_w + (size_t)i * 64 * DIN_, xpwT + (size_t)i * DIN_ * DTR_);
  for (int i = 0; i < NB_; ++i) {
    mgemm_k<0, 0, 128, 0><<<dim3(8, 8), blk, 0, stream>>>(
        dt_proj_w + (size_t)i * DIN_ * DTR_, xpwT + (size_t)i * DIN_ * DTR_,
        nullptr, wcT, 1024, 1024, 32, 32, 1024);
    pack_k<<<dim3(1152 * 1024 / 256), blk, 0, stream>>>(
        wcT, x_proj_w + (size_t)i * 64 * DIN_, wBig + (size_t)i * 1152 * 1024);
  }

  // ---- temporal conv (GEMM + fused im2col) + LN(hc + x) -> h ----
  mgemm_k<1, 1, 64, 1><<<dim3(8, 64), blk, 0, stream>>>(
      x, wTT, tconv_b, xin, M_, 512, 1536, 0, 512);
  ln_k<1, 0><<<dim3(M_), blk, 0, stream>>>(xin, x, tnorm_w, tnorm_b, h);

  for (int i = 0; i < NB_; ++i) {
    // xin = LN(h)  (bf16)
    ln_k<0, 1><<<dim3(M_), blk, 0, stream>>>(h, nullptr, ln1_w + i * D_, ln1_b + i * D_, xin);
    // xz = xin @ in_proj^T  (bf16)
    mgemm2_k<128, 0, 1><<<dim3(16, 64), blk, 0, stream>>>(
        xin, wIP + (size_t)i * 2048 * 512, nullptr, xzb, nullptr,
        M_, 2048, 512, 512, 2048);
    // u = silu(dwconv(xz_u) + cb)  (bf16)
    dwconv_k<<<dim3(M_ * DIN_ / 8 / 256), blk, 0, stream>>>(
        xzb, conv_w + (size_t)i * DIN_ * 4, conv_b + (size_t)i * DIN_, ubuf);
    // dt (softplus, fp32) + B/C (fp32) in one GEMM vs Wbig (N padded to 1152)
    mgemm2_k<128, 6, 0><<<dim3(9, 64), blk, 0, stream>>>(
        ubuf, wBig + (size_t)i * 1152 * 1024, dt_proj_b + (size_t)i * DIN_,
        dtb, bc, M_, 1152, 1024, 1024, 1024);
    // selective scan; ys overwrites u in place (bf16)
    scan5_k<<<dim3(B_ * (DIN_ / SC_G)), dim3(512), 0, stream>>>(
        dtb, ubuf, bc, xzb, A_log + (size_t)i * DIN_ * NST_, D_param + (size_t)i * DIN_);
    // h += ys @ out_proj^T
    mgemm2_k<64, 4, 0><<<dim3(4, 128), blk, 0, stream>>>(
        ubuf, wOP + (size_t)i * 512 * 1024, nullptr, h, nullptr,
        M_, 512, 1024, 1024, 512);
    // hn = LN(h) (bf16); ff = gelu(hn @ w1^T + b1) (bf16); h += ff @ w2^T + b2
    ln_k<0, 1><<<dim3(M_), blk, 0, stream>>>(h, nullptr, ln2_w + i * D_, ln2_b + i * D_, xin);
    mgemm2_k<128, 2, 1><<<dim3(8, 64), blk, 0, stream>>>(
        xin, wF1 + (size_t)i * 1024 * 512, ffn_b1 + (size_t)i * FF_, ff, nullptr,
        M_, 1024, 512, 512, 1024);
    mgemm2_k<64, 5, 0><<<dim3(4, 128), blk, 0, stream>>>(
        ff, wF2 + (size_t)i * 512 * 1024, ffn_b2 + (size_t)i * D_, h, nullptr,
        M_, 512, 1024, 1024, 512);
  }
}

// Round 8
// 1236.076 us; speedup vs baseline: 5.1897x; 1.1249x over previous
//
#include <hip/hip_runtime.h>
#include <hip/hip_bf16.h>
#include <math.h>

#define B_ 8
#define L_ 1024
#define D_ 512
#define NB_ 4
#define DIN_ 1024
#define NST_ 16
#define DTR_ 32
#define FF_ 1024
#define EPS_LN 1e-5f
#define M_ (B_ * L_)

#define SC_G 16                 // channels per scan block
#define SC_C 32                 // L-chunks per scan block
#define SC_LEN (L_ / SC_C)      // 32 steps per chunk

typedef __attribute__((ext_vector_type(8))) short short8;
typedef __attribute__((ext_vector_type(4))) float f32x4;

static __device__ __forceinline__ ushort f2bf(float f) {
  union { float f; unsigned u; } v; v.f = f;
  unsigned r = v.u + 0x7FFFu + ((v.u >> 16) & 1u);
  return (ushort)(r >> 16);
}
static __device__ __forceinline__ float bf2f(ushort u) {
  union { unsigned u; float f; } v; v.u = ((unsigned)u) << 16;
  return v.f;
}

// async global->LDS, 16B per lane; LDS dest is wave-uniform base + lane*16
static __device__ __forceinline__ void gll16(const void* g, void* l) {
  __builtin_amdgcn_global_load_lds(
      (const __attribute__((address_space(1))) void*)g,
      (__attribute__((address_space(3))) void*)l, 16, 0, 0);
}

// ---------------------------------------------------------------------------
// Fast bf16 MFMA GEMM (A,W both bf16):  C = epi(A @ W^T (+bias))
// BK=64, BN=128, 256 threads = 4 waves (2x2), global_load_lds staging with
// source-side XOR swizzle (slot j ^= row&7 -> ds_read_b128 2-way, free).
// XCD-aware block swizzle (M-major linearization, requires nwg % 8 == 0).
// MODE 0: A[m*lda+k].  MODE 1: im2col from bf16 xpad (B,(L+2),D), pad row 0/1025.
// BM in {64,128}. EPI: 0 store, 1 +bias, 2 +bias+gelu, 4 C+=, 5 C+=+bias,
//   6 dual-out: n<1024 softplus(+bias)->Cp bf16; 1024..1055 -> C2 bf16; else skip.
// OUTB: bf16 store (EPI 0/1/2).
// ---------------------------------------------------------------------------
template <int MODE, int BM, int EPI, int OUTB>
__global__ __launch_bounds__(256) void mgemm2_k(
    const ushort* __restrict__ A, const ushort* __restrict__ W,
    const float* __restrict__ bias, void* __restrict__ Cp,
    ushort* __restrict__ C2, int M, int N, int K, int lda, int ldc)
{
  constexpr int MI = BM / 32;
  __shared__ ushort As[BM * 64];
  __shared__ ushort Bs[128 * 64];
  const int tid = threadIdx.x;
  const int lane = tid & 63;
  const int wid = tid >> 6;
  const int wm = (wid >> 1) * (BM / 2);
  const int wn = (wid & 1) * 64;

  // XCD-aware swizzle: chunk the M-major linear workspace across 8 XCDs
  const int gx = gridDim.x;
  const int nwg = gx * gridDim.y;
  int wg = blockIdx.y * gx + blockIdx.x;
  wg = (wg & 7) * (nwg >> 3) + (wg >> 3);
  const int bm = (wg / gx) * BM;
  const int bn = (wg % gx) * 128;

  const int fr = lane & 15;
  const int kq = lane >> 4;

  f32x4 acc[MI][4];
#pragma unroll
  for (int i = 0; i < MI; ++i)
#pragma unroll
    for (int j = 0; j < 4; ++j) acc[i][j] = (f32x4)0.f;

  for (int k0 = 0; k0 < K; k0 += 64) {
    // ---- stage A (BM x 64 bf16): BM/32 wave-issues ----
#pragma unroll
    for (int it = 0; it < BM / 32; ++it) {
      const int sb = it * 4096 + wid * 1024 + lane * 16;  // byte in tile
      const int row = sb >> 7;
      const int js = (sb >> 4) & 7;
      const int j2 = js ^ (row & 7);                      // pre-swizzled src
      const ushort* src;
      if (MODE == 0) {
        src = A + (size_t)(bm + row) * lda + k0 + j2 * 8;
      } else {
        const int k = k0 + j2 * 8;
        const int tap = k >> 9;
        const int dcol = k & 511;
        const int m = bm + row;
        const int bq = m >> 10;
        const int l = m & (L_ - 1);
        src = A + ((size_t)bq * (L_ + 2) + l + tap) * D_ + dcol;
      }
      gll16(src, (char*)As + it * 4096 + wid * 1024);
    }
    // ---- stage B (128 x 64 bf16 = 16KB): 4 wave-issues ----
#pragma unroll
    for (int it = 0; it < 4; ++it) {
      const int sb = it * 4096 + wid * 1024 + lane * 16;
      const int row = sb >> 7;
      const int js = (sb >> 4) & 7;
      const int j2 = js ^ (row & 7);
      gll16(W + (size_t)(bn + row) * K + k0 + j2 * 8,
            (char*)Bs + it * 4096 + wid * 1024);
    }
    __syncthreads();
#pragma unroll
    for (int kk = 0; kk < 2; ++kk) {
      short8 af[MI], bf[4];
#pragma unroll
      for (int mi = 0; mi < MI; ++mi) {
        const int r = wm + mi * 16 + fr;
        af[mi] = *(const short8*)&As[r * 64 + ((((kk << 2) + kq) ^ (r & 7)) << 3)];
      }
#pragma unroll
      for (int ni = 0; ni < 4; ++ni) {
        const int r = wn + ni * 16 + fr;
        bf[ni] = *(const short8*)&Bs[r * 64 + ((((kk << 2) + kq) ^ (r & 7)) << 3)];
      }
#pragma unroll
      for (int mi = 0; mi < MI; ++mi)
#pragma unroll
        for (int ni = 0; ni < 4; ++ni)
          acc[mi][ni] = __builtin_amdgcn_mfma_f32_16x16x32_bf16(
              af[mi], bf[ni], acc[mi][ni], 0, 0, 0);
    }
    __syncthreads();
  }

  // ---- epilogue: D layout col=lane&15, row=(lane>>4)*4+reg ----
#pragma unroll
  for (int mi = 0; mi < MI; ++mi) {
#pragma unroll
    for (int ni = 0; ni < 4; ++ni) {
#pragma unroll
      for (int r = 0; r < 4; ++r) {
        const int gm = bm + wm + mi * 16 + (lane >> 4) * 4 + r;
        const int gn = bn + wn + ni * 16 + fr;
        float v = acc[mi][ni][r];
        if (EPI == 6) {
          if (gn < DIN_) {
            v += bias[gn];
            v = (v > 20.f) ? v : __logf(1.f + __expf(v));
            ((ushort*)Cp)[(size_t)gm * DIN_ + gn] = f2bf(v);
          } else if (gn < DIN_ + 2 * NST_) {
            C2[(size_t)gm * (2 * NST_) + (gn - DIN_)] = f2bf(v);
          }
        } else {
          if (EPI == 1 || EPI == 2 || EPI == 5) v += bias[gn];
          if (EPI == 2) v = 0.5f * v * (1.f + erff(v * 0.70710678118654752f));
          if (OUTB) {
            ((ushort*)Cp)[(size_t)gm * ldc + gn] = f2bf(v);
          } else {
            float* pc = (float*)Cp + (size_t)gm * ldc + gn;
            if (EPI == 4 || EPI == 5) v += *pc;
            *pc = v;
          }
        }
      }
    }
  }
}

// ---------------------------------------------------------------------------
// Legacy GEMM (fp32-A path, used only for Wcomb preproc), BK=32, reg staging.
// ---------------------------------------------------------------------------
template <int EPI, int BN, int OUTB>
__global__ __launch_bounds__(256) void mgemm_k(
    const float* __restrict__ Ap, const ushort* __restrict__ W,
    const float* __restrict__ bias, void* __restrict__ Cp,
    int M, int N, int K, int lda, int ldc)
{
  constexpr int FN = BN / 32;
  __shared__ ushort As[128 * 32];
  __shared__ ushort Bs[BN * 32];
  const int tid = threadIdx.x;
  const int lane = tid & 63;
  const int wid = tid >> 6;
  const int wm = (wid >> 1) * 64;
  const int wn = (wid & 1) * (BN / 2);
  const int bm = blockIdx.y * 128;
  const int bn = blockIdx.x * BN;
  const int fr = lane & 15;
  const int kq = lane >> 4;

  f32x4 acc[4][FN];
#pragma unroll
  for (int i = 0; i < 4; ++i)
#pragma unroll
    for (int j = 0; j < FN; ++j) acc[i][j] = (f32x4)0.f;

  for (int k0 = 0; k0 < K; k0 += 32) {
#pragma unroll
    for (int it = 0; it < 2; ++it) {
      const int idx = tid + it * 256;
      const int row = idx >> 2;
      const int j = idx & 3;
      short8 s;
      const float* p = Ap + (size_t)(bm + row) * lda + k0 + j * 8;
      const float4 v0 = *(const float4*)p;
      const float4 v1 = *(const float4*)(p + 4);
      s[0] = (short)f2bf(v0.x); s[1] = (short)f2bf(v0.y);
      s[2] = (short)f2bf(v0.z); s[3] = (short)f2bf(v0.w);
      s[4] = (short)f2bf(v1.x); s[5] = (short)f2bf(v1.y);
      s[6] = (short)f2bf(v1.z); s[7] = (short)f2bf(v1.w);
      *(short8*)&As[row * 32 + ((j ^ ((row >> 1) & 3)) << 3)] = s;
    }
#pragma unroll
    for (int it = 0; it < BN / 64; ++it) {
      const int idx = tid + it * 256;
      const int row = idx >> 2;
      const int j = idx & 3;
      short8 s = *(const short8*)(W + (size_t)(bn + row) * K + k0 + j * 8);
      *(short8*)&Bs[row * 32 + ((j ^ ((row >> 1) & 3)) << 3)] = s;
    }
    __syncthreads();
    short8 af[4], bfr[FN];
#pragma unroll
    for (int mi = 0; mi < 4; ++mi) {
      const int r = wm + mi * 16 + fr;
      af[mi] = *(const short8*)&As[r * 32 + ((kq ^ ((r >> 1) & 3)) << 3)];
    }
#pragma unroll
    for (int ni = 0; ni < FN; ++ni) {
      const int r = wn + ni * 16 + fr;
      bfr[ni] = *(const short8*)&Bs[r * 32 + ((kq ^ ((r >> 1) & 3)) << 3)];
    }
#pragma unroll
    for (int mi = 0; mi < 4; ++mi)
#pragma unroll
      for (int ni = 0; ni < FN; ++ni)
        acc[mi][ni] = __builtin_amdgcn_mfma_f32_16x16x32_bf16(
            af[mi], bfr[ni], acc[mi][ni], 0, 0, 0);
    __syncthreads();
  }

#pragma unroll
  for (int mi = 0; mi < 4; ++mi) {
#pragma unroll
    for (int ni = 0; ni < FN; ++ni) {
#pragma unroll
      for (int r = 0; r < 4; ++r) {
        const int gm = bm + wm + mi * 16 + (lane >> 4) * 4 + r;
        const int gn = bn + wn + ni * 16 + fr;
        float v = acc[mi][ni][r];
        if (EPI == 1) v += bias[gn];
        if (OUTB) ((ushort*)Cp)[(size_t)gm * ldc + gn] = f2bf(v);
        else ((float*)Cp)[(size_t)gm * ldc + gn] = v;
      }
    }
  }
}

// ---------------------------------------------------------------------------
// LayerNorm over last dim 512. INB: input bf16. OUTB: output bf16.
// ---------------------------------------------------------------------------
template <int INB, int OUTB>
__global__ __launch_bounds__(256) void ln_k(
    const void* __restrict__ inp, const float* __restrict__ res,
    const float* __restrict__ w, const float* __restrict__ b,
    void* __restrict__ outp)
{
  const int row = blockIdx.x;
  const int t = threadIdx.x;
  float v0, v1;
  if (INB) {
    const ushort* p = (const ushort*)inp + (size_t)row * D_;
    v0 = bf2f(p[t]); v1 = bf2f(p[t + 256]);
  } else {
    const float* p = (const float*)inp + (size_t)row * D_;
    v0 = p[t]; v1 = p[t + 256];
  }
  if (res) {
    const float* r = res + (size_t)row * D_;
    v0 += r[t]; v1 += r[t + 256];
  }
  float s = v0 + v1;
  float sq = v0 * v0 + v1 * v1;
#pragma unroll
  for (int m = 1; m < 64; m <<= 1) {
    s += __shfl_xor(s, m, 64);
    sq += __shfl_xor(sq, m, 64);
  }
  __shared__ float ss[4], qq[4];
  const int wid = t >> 6;
  if ((t & 63) == 0) { ss[wid] = s; qq[wid] = sq; }
  __syncthreads();
  s = ss[0] + ss[1] + ss[2] + ss[3];
  sq = qq[0] + qq[1] + qq[2] + qq[3];
  const float mu = s * (1.f / (float)D_);
  const float var = sq * (1.f / (float)D_) - mu * mu;
  const float rs = rsqrtf(var + EPS_LN);
  const float o0 = (v0 - mu) * rs * w[t] + b[t];
  const float o1 = (v1 - mu) * rs * w[t + 256] + b[t + 256];
  if (OUTB) {
    ushort* o = (ushort*)outp + (size_t)row * D_;
    o[t] = f2bf(o0); o[t + 256] = f2bf(o1);
  } else {
    float* o = (float*)outp + (size_t)row * D_;
    o[t] = o0; o[t + 256] = o1;
  }
}

// ---------------------------------------------------------------------------
// Depthwise causal conv (k=4, pad 3), vectorized 8 channels/thread.
// ---------------------------------------------------------------------------
__global__ __launch_bounds__(256) void dwconv_k(
    const ushort* __restrict__ xz, const float* __restrict__ cw,
    const float* __restrict__ cb, ushort* __restrict__ u)
{
  const int idx = blockIdx.x * 256 + threadIdx.x;   // M_*DIN_/8 threads
  const int c8 = idx & (DIN_ / 8 - 1);
  const int bl = idx >> 7;
  const int l = bl & (L_ - 1);
  const int b0 = bl - l;
  const int c0 = c8 * 8;
  float s[8], w[8][4];
#pragma unroll
  for (int j = 0; j < 8; ++j) {
    s[j] = cb[c0 + j];
    const float4 wv = *(const float4*)(cw + (c0 + j) * 4);
    w[j][0] = wv.x; w[j][1] = wv.y; w[j][2] = wv.z; w[j][3] = wv.w;
  }
#pragma unroll
  for (int k = 0; k < 4; ++k) {
    const int ll = l + k - 3;
    if (ll >= 0) {
      const short8 v = *(const short8*)(xz + (size_t)(b0 + ll) * (2 * DIN_) + c0);
#pragma unroll
      for (int j = 0; j < 8; ++j)
        s[j] = fmaf(bf2f((ushort)v[j]), w[j][k], s[j]);
    }
  }
  short8 o;
#pragma unroll
  for (int j = 0; j < 8; ++j) {
    const float t = s[j] / (1.f + __expf(-s[j]));
    o[j] = (short)f2bf(t);
  }
  *(short8*)(u + (size_t)idx * 8) = o;
}

// ---------------------------------------------------------------------------
// Selective scan: dA[n] = exp(dt*A[n]).
// FAST path exploits A[n] = (n+1)*A[0]: 1 exp + squaring tree (depth <=4).
// ---------------------------------------------------------------------------
template <bool FAST>
static __device__ __forceinline__ void dAcalc(float dtv, float A0,
                                              const float* A, float* dA)
{
  if (FAST) {
    const float e1 = __expf(dtv * A0);
    const float e2 = e1 * e1, e4 = e2 * e2, e8 = e4 * e4, e16 = e8 * e8;
#pragma unroll
    for (int n = 0; n < 16; ++n) {
      const int pp = n + 1;
      float v = 1.f;
      if (pp & 1) v *= e1;
      if (pp & 2) v *= e2;
      if (pp & 4) v *= e4;
      if (pp & 8) v *= e8;
      if (pp & 16) v *= e16;
      dA[n] = v;
    }
  } else {
#pragma unroll
    for (int n = 0; n < 16; ++n) dA[n] = __expf(dtv * A[n]);
  }
}

static __device__ __forceinline__ void ldbf16x16(const ushort* p, float* dst) {
  const short8 s0 = *(const short8*)p;
  const short8 s1 = *(const short8*)(p + 8);
#pragma unroll
  for (int n = 0; n < 8; ++n) {
    dst[n] = bf2f((ushort)s0[n]);
    dst[n + 8] = bf2f((ushort)s1[n]);
  }
}

template <bool FAST>
static __device__ __forceinline__ void scan_run(
    const ushort* __restrict__ dt, ushort* __restrict__ u,
    const ushort* __restrict__ BC, const ushort* __restrict__ xz,
    const float* __restrict__ A_log,
    const float* A, const float A0, const float Dpd,
    float (*Hs)[SC_G][NST_ + 1], float (*Ss)[SC_G],
    const int tid, const int g, const int c, const int d0, const int d,
    const size_t base)
{
  const int l0 = c * SC_LEN;
  float h[16];
#pragma unroll
  for (int n = 0; n < 16; ++n) h[n] = 0.f;
  float S = 0.f;

  // ---------------- pass 1: local scan + decay sum ----------------
#pragma unroll 4
  for (int i = 0; i < SC_LEN; ++i) {
    const size_t row = base + l0 + i;
    const float dtv = bf2f(dt[row * DIN_ + d]);
    const float uv = bf2f(u[row * DIN_ + d]);
    float Bv[16];
    ldbf16x16(BC + row * 32, Bv);
    S += dtv;
    const float du = dtv * uv;
    float dA[16];
    dAcalc<FAST>(dtv, A0, A, dA);
#pragma unroll
    for (int n = 0; n < 16; ++n)
      h[n] = fmaf(dA[n], h[n], du * Bv[n]);
  }
#pragma unroll
  for (int n = 0; n < 16; ++n) Hs[c][g][n] = h[n];
  Ss[c][g] = S;
  __syncthreads();

  // ---------------- serial chunk combine ((channel,state) pairs) ----------
  if (tid < SC_G * NST_) {
    const int gg = tid >> 4;
    const int n2 = tid & 15;
    const float An = -expf(A_log[(d0 + gg) * NST_ + n2]);
    float hin = 0.f;
#pragma unroll
    for (int cc = 0; cc < SC_C; ++cc) {
      const float tmp = Hs[cc][gg][n2];
      const float P = __expf(An * Ss[cc][gg]);
      Hs[cc][gg][n2] = hin;
      hin = tmp + P * hin;
    }
  }
  __syncthreads();

  // ---------------- pass 2: recompute with incoming state, emit y ---------
#pragma unroll
  for (int n = 0; n < 16; ++n) h[n] = Hs[c][g][n];
#pragma unroll 4
  for (int i = 0; i < SC_LEN; ++i) {
    const size_t row = base + l0 + i;
    const float dtv = bf2f(dt[row * DIN_ + d]);
    const float uv = bf2f(u[row * DIN_ + d]);
    const float zv = bf2f(xz[row * (2 * DIN_) + DIN_ + d]);
    float Bv[16], Cv[16];
    ldbf16x16(BC + row * 32, Bv);
    ldbf16x16(BC + row * 32 + 16, Cv);
    const float du = dtv * uv;
    float y = uv * Dpd;
    float dA[16];
    dAcalc<FAST>(dtv, A0, A, dA);
#pragma unroll
    for (int n = 0; n < 16; ++n) {
      h[n] = fmaf(dA[n], h[n], du * Bv[n]);
      y = fmaf(h[n], Cv[n], y);
    }
    y *= zv / (1.f + __expf(-zv));
    u[row * DIN_ + d] = f2bf(y);
  }
}

// Block = (b, 16-channel group). 512 thr = 16 channels x 32 chunks (32 steps).
__global__ __launch_bounds__(512) void scan6_k(
    const ushort* __restrict__ dt, ushort* u,
    const ushort* __restrict__ BC, const ushort* __restrict__ xz,
    const float* __restrict__ A_log, const float* __restrict__ Dp)
{
  const int tid = threadIdx.x;
  const int g = tid & (SC_G - 1);
  const int c = tid >> 4;
  const int b = blockIdx.x >> 6;
  const int d0 = (blockIdx.x & 63) * SC_G;
  const int d = d0 + g;

  __shared__ float Hs[SC_C][SC_G][NST_ + 1];
  __shared__ float Ss[SC_C][SC_G];
  __shared__ int slow;
  if (tid == 0) slow = 0;
  __syncthreads();

  float A[16];
#pragma unroll
  for (int n = 0; n < 16; ++n) A[n] = -expf(A_log[d * NST_ + n]);
  const float A0 = A[0];
  bool myfast = true;
#pragma unroll
  for (int n = 1; n < 16; ++n)
    myfast = myfast && (fabsf(A[n] - (float)(n + 1) * A0) <= 1e-3f * fabsf(A[n]));
  if (!myfast) slow = 1;
  __syncthreads();
  const float Dpd = Dp[d];
  const size_t base = (size_t)b * L_;

  if (slow == 0)
    scan_run<true>(dt, u, BC, xz, A_log, A, A0, Dpd, Hs, Ss, tid, g, c, d0, d, base);
  else
    scan_run<false>(dt, u, BC, xz, A_log, A, A0, Dpd, Hs, Ss, tid, g, c, d0, d, base);
}

// ---------------------------------------------------------------------------
// Small helper kernels
// ---------------------------------------------------------------------------
__global__ __launch_bounds__(256) void cvt_k(const float* __restrict__ in,
                                             ushort* __restrict__ out, int n8)
{
  const int i = blockIdx.x * 256 + threadIdx.x;
  if (i >= n8) return;
  const float4 a = *(const float4*)(in + (size_t)i * 8);
  const float4 b = *(const float4*)(in + (size_t)i * 8 + 4);
  short8 s;
  s[0] = (short)f2bf(a.x); s[1] = (short)f2bf(a.y);
  s[2] = (short)f2bf(a.z); s[3] = (short)f2bf(a.w);
  s[4] = (short)f2bf(b.x); s[5] = (short)f2bf(b.y);
  s[6] = (short)f2bf(b.z); s[7] = (short)f2bf(b.w);
  *(short8*)(out + (size_t)i * 8) = s;
}

// x (B,L,D) fp32 -> xpad (B, L+2, D) bf16 with zero rows at l=-1 and l=L
__global__ __launch_bounds__(256) void padx_k(const float* __restrict__ x,
                                              ushort* __restrict__ xpad)
{
  const int i = blockIdx.x * 256 + threadIdx.x;   // B*(L+2)*D/8 = 525312
  const int row = i >> 6;                         // 0..8207
  const int c0 = (i & 63) * 8;
  const int b = row / (L_ + 2);
  const int r = row - b * (L_ + 2);
  short8 s = {0, 0, 0, 0, 0, 0, 0, 0};
  if (r != 0 && r != L_ + 1) {
    const float* p = x + ((size_t)b * L_ + (r - 1)) * D_ + c0;
    const float4 a = *(const float4*)p;
    const float4 bb = *(const float4*)(p + 4);
    s[0] = (short)f2bf(a.x); s[1] = (short)f2bf(a.y);
    s[2] = (short)f2bf(a.z); s[3] = (short)f2bf(a.w);
    s[4] = (short)f2bf(bb.x); s[5] = (short)f2bf(bb.y);
    s[6] = (short)f2bf(bb.z); s[7] = (short)f2bf(bb.w);
  }
  *(short8*)(xpad + (size_t)row * D_ + c0) = s;
}

// tconv_w (O,I,3) -> bf16 (O, tap*512 + d)
__global__ __launch_bounds__(256) void twt_k(const float* __restrict__ in,
                                             ushort* __restrict__ out)
{
  const int i = blockIdx.x * 256 + threadIdx.x;
  if (i >= D_ * D_ * 3) return;
  const int o = i / (D_ * 3);
  const int rem = i - o * (D_ * 3);
  const int d = rem / 3;
  const int tap = rem - d * 3;
  out[(size_t)o * (D_ * 3) + tap * D_ + d] = f2bf(in[i]);
}

// x_proj_w[0:32] (32,1024) -> bf16 transpose (1024,32)
__global__ __launch_bounds__(256) void xpT_k(const float* __restrict__ xpw,
                                             ushort* __restrict__ out)
{
  const int i = blockIdx.x * 256 + threadIdx.x;
  if (i >= DIN_ * DTR_) return;
  const int k = i >> 5;
  const int r = i & 31;
  out[i] = f2bf(xpw[(size_t)r * DIN_ + k]);
}

// Wbig (1152,1024) bf16 = [Wcomb (1024); x_proj_w[32:64] (32); zeros(96)]
__global__ __launch_bounds__(256) void pack_k(const float* __restrict__ wc,
                                              const float* __restrict__ xpw,
                                              ushort* __restrict__ wbig)
{
  const int i = blockIdx.x * 256 + threadIdx.x;
  if (i >= 1152 * 1024) return;
  const int r = i >> 10;
  const int k = i & 1023;
  float v;
  if (r < 1024) v = wc[i];
  else if (r < 1056) v = xpw[(size_t)(DTR_ + r - 1024) * DIN_ + k];
  else v = 0.f;
  wbig[i] = f2bf(v);
}

// ---------------------------------------------------------------------------
extern "C" void kernel_launch(void* const* d_in, const int* in_sizes, int n_in,
                              void* d_out, int out_size, void* d_ws, size_t ws_size,
                              hipStream_t stream)
{
  const float* x         = (const float*)d_in[0];
  const float* tconv_w   = (const float*)d_in[1];
  const float* tconv_b   = (const float*)d_in[2];
  const float* tnorm_w   = (const float*)d_in[3];
  const float* tnorm_b   = (const float*)d_in[4];
  const float* ln1_w     = (const float*)d_in[5];
  const float* ln1_b     = (const float*)d_in[6];
  const float* in_proj_w = (const float*)d_in[7];
  const float* conv_w    = (const float*)d_in[8];
  const float* conv_b    = (const float*)d_in[9];
  const float* x_proj_w  = (const float*)d_in[10];
  const float* dt_proj_w = (const float*)d_in[11];
  const float* dt_proj_b = (const float*)d_in[12];
  const float* A_log     = (const float*)d_in[13];
  const float* D_param   = (const float*)d_in[14];
  const float* out_proj_w= (const float*)d_in[15];
  const float* ln2_w     = (const float*)d_in[16];
  const float* ln2_b     = (const float*)d_in[17];
  const float* ffn_w1    = (const float*)d_in[18];
  const float* ffn_b1    = (const float*)d_in[19];
  const float* ffn_w2    = (const float*)d_in[20];
  const float* ffn_b2    = (const float*)d_in[21];

  float* h = (float*)d_out;

  // ---- workspace layout ----
  char* p = (char*)d_ws;
  ushort* wTT  = (ushort*)p; p += (size_t)512 * 1536 * 2;
  ushort* wIP  = (ushort*)p; p += (size_t)4 * 2048 * 512 * 2;
  ushort* wOP  = (ushort*)p; p += (size_t)4 * 512 * 1024 * 2;
  ushort* wF1  = (ushort*)p; p += (size_t)4 * 1024 * 512 * 2;
  ushort* wF2  = (ushort*)p; p += (size_t)4 * 512 * 1024 * 2;
  ushort* xpwT = (ushort*)p; p += (size_t)4 * 1024 * 32 * 2;
  ushort* wBig = (ushort*)p; p += (size_t)4 * 1152 * 1024 * 2;
  float*  wcT  = (float*)p;  p += (size_t)1024 * 1024 * 4;
  ushort* xpad = (ushort*)p; p += (size_t)B_ * (L_ + 2) * D_ * 2;
  ushort* xin  = (ushort*)p; p += (size_t)M_ * 512 * 2;
  ushort* xzb  = (ushort*)p; p += (size_t)M_ * 2048 * 2;
  ushort* ubuf = (ushort*)p; p += (size_t)M_ * 1024 * 2;
  ushort* bc   = (ushort*)p; p += (size_t)M_ * 32 * 2;
  ushort* dtb  = (ushort*)p; p += (size_t)M_ * 1024 * 2;
  ushort* ff   = (ushort*)p; p += (size_t)M_ * 1024 * 2;

  const dim3 blk(256);

  // ---- preprocessing: weights -> bf16, Wcomb = dt_proj_w @ x_proj_w[0:32] ----
  cvt_k<<<dim3(4 * 2048 * 512 / 8 / 256), blk, 0, stream>>>(in_proj_w, wIP, 4 * 2048 * 512 / 8);
  cvt_k<<<dim3(4 * 512 * 1024 / 8 / 256), blk, 0, stream>>>(out_proj_w, wOP, 4 * 512 * 1024 / 8);
  cvt_k<<<dim3(4 * 1024 * 512 / 8 / 256), blk, 0, stream>>>(ffn_w1, wF1, 4 * 1024 * 512 / 8);
  cvt_k<<<dim3(4 * 512 * 1024 / 8 / 256), blk, 0, stream>>>(ffn_w2, wF2, 4 * 512 * 1024 / 8);
  twt_k<<<dim3((D_ * D_ * 3 + 255) / 256), blk, 0, stream>>>(tconv_w, wTT);
  padx_k<<<dim3(B_ * (L_ + 2) * D_ / 8 / 256), blk, 0, stream>>>(x, xpad);
  for (int i = 0; i < NB_; ++i)
    xpT_k<<<dim3(DIN_ * DTR_ / 256), blk, 0, stream>>>(
        x_proj_w + (size_t)i * 64 * DIN_, xpwT + (size_t)i * DIN_ * DTR_);
  for (int i = 0; i < NB_; ++i) {
    mgemm_k<0, 128, 0><<<dim3(8, 8), blk, 0, stream>>>(
        dt_proj_w + (size_t)i * DIN_ * DTR_, xpwT + (size_t)i * DIN_ * DTR_,
        nullptr, wcT, 1024, 1024, 32, 32, 1024);
    pack_k<<<dim3(1152 * 1024 / 256), blk, 0, stream>>>(
        wcT, x_proj_w + (size_t)i * 64 * DIN_, wBig + (size_t)i * 1152 * 1024);
  }

  // ---- temporal conv (GEMM + fused im2col from xpad) + LN(hc + x) -> h ----
  mgemm2_k<1, 128, 1, 1><<<dim3(4, 64), blk, 0, stream>>>(
      xpad, wTT, tconv_b, xin, nullptr, M_, 512, 1536, 0, 512);
  ln_k<1, 0><<<dim3(M_), blk, 0, stream>>>(xin, x, tnorm_w, tnorm_b, h);

  for (int i = 0; i < NB_; ++i) {
    // xin = LN(h)  (bf16)
    ln_k<0, 1><<<dim3(M_), blk, 0, stream>>>(h, nullptr, ln1_w + i * D_, ln1_b + i * D_, xin);
    // xz = xin @ in_proj^T  (bf16)
    mgemm2_k<0, 128, 0, 1><<<dim3(16, 64), blk, 0, stream>>>(
        xin, wIP + (size_t)i * 2048 * 512, nullptr, xzb, nullptr,
        M_, 2048, 512, 512, 2048);
    // u = silu(dwconv(xz_u) + cb)  (bf16)
    dwconv_k<<<dim3(M_ * DIN_ / 8 / 256), blk, 0, stream>>>(
        xzb, conv_w + (size_t)i * DIN_ * 4, conv_b + (size_t)i * DIN_, ubuf);
    // dt (softplus, bf16) + B/C (bf16) in one GEMM vs Wbig (N padded to 1152)
    mgemm2_k<0, 64, 6, 0><<<dim3(9, 128), blk, 0, stream>>>(
        ubuf, wBig + (size_t)i * 1152 * 1024, dt_proj_b + (size_t)i * DIN_,
        dtb, bc, M_, 1152, 1024, 1024, 1024);
    // selective scan; ys overwrites u in place (bf16)
    scan6_k<<<dim3(B_ * (DIN_ / SC_G)), dim3(512), 0, stream>>>(
        dtb, ubuf, bc, xzb, A_log + (size_t)i * DIN_ * NST_, D_param + (size_t)i * DIN_);
    // h += ys @ out_proj^T
    mgemm2_k<0, 64, 4, 0><<<dim3(4, 128), blk, 0, stream>>>(
        ubuf, wOP + (size_t)i * 512 * 1024, nullptr, h, nullptr,
        M_, 512, 1024, 1024, 512);
    // hn = LN(h) (bf16); ff = gelu(hn @ w1^T + b1) (bf16); h += ff @ w2^T + b2
    ln_k<0, 1><<<dim3(M_), blk, 0, stream>>>(h, nullptr, ln2_w + i * D_, ln2_b + i * D_, xin);
    mgemm2_k<0, 64, 2, 1><<<dim3(8, 128), blk, 0, stream>>>(
        xin, wF1 + (size_t)i * 1024 * 512, ffn_b1 + (size_t)i * FF_, ff, nullptr,
        M_, 1024, 512, 512, 1024);
    mgemm2_k<0, 64, 5, 0><<<dim3(4, 128), blk, 0, stream>>>(
        ff, wF2 + (size_t)i * 512 * 1024, ffn_b2 + (size_t)i * D_, h, nullptr,
        M_, 512, 1024, 1024, 512);
  }
}